// Round 1
// baseline (1757.745 us; speedup 1.0000x reference)
//
#include <hip/hip_runtime.h>
#include <cstdint>
#include <cstddef>

#define IN_DIM  768
#define NNODES  10000
#define NEDGES  80000
#define E_TOT   90000        // edges + self loops
#define HEADS   8
#define HID     256
#define HC      2048         // HEADS*HID
#define NEG_SLOPE 0.2f

// ---------------------------------------------------------------------------
// edge helpers: edge ids [0,NEDGES) are real edges, [NEDGES,E_TOT) self loops
// ---------------------------------------------------------------------------
__device__ __forceinline__ int edge_src(const int* __restrict__ ei, int e) {
    return (e < NEDGES) ? ei[e] : (e - NEDGES);
}
__device__ __forceinline__ int edge_dst(const int* __restrict__ ei, int e) {
    return (e < NEDGES) ? ei[NEDGES + e] : (e - NEDGES);
}

// ---------------------------------------------------------------------------
// CSR build: count -> scan -> scatter (int atomics only; fp path is gather)
// ---------------------------------------------------------------------------
__global__ void count_kernel(const int* __restrict__ ei, int* __restrict__ cnt) {
    int e = blockIdx.x * 256 + threadIdx.x;
    if (e < E_TOT) atomicAdd(&cnt[edge_dst(ei, e)], 1);
}

__global__ void scan_kernel(const int* __restrict__ cnt, int* __restrict__ indptr) {
    __shared__ int sums[1024];
    const int CH = 10;                      // 1024*10 >= 10000
    int t = threadIdx.x;
    int base = t * CH;
    int s = 0;
#pragma unroll
    for (int i = 0; i < CH; i++) { int idx = base + i; if (idx < NNODES) s += cnt[idx]; }
    sums[t] = s;
    __syncthreads();
    for (int off = 1; off < 1024; off <<= 1) {
        int v = (t >= off) ? sums[t - off] : 0;
        __syncthreads();
        sums[t] += v;
        __syncthreads();
    }
    int run = (t == 0) ? 0 : sums[t - 1];   // exclusive prefix
#pragma unroll
    for (int i = 0; i < CH; i++) {
        int idx = base + i;
        if (idx < NNODES) { indptr[idx] = run; run += cnt[idx]; }
    }
    if (t == 0) indptr[NNODES] = E_TOT;
}

__global__ void scatter_kernel(const int* __restrict__ ei, const int* __restrict__ indptr,
                               int* __restrict__ cur, int* __restrict__ sorted) {
    int e = blockIdx.x * 256 + threadIdx.x;
    if (e < E_TOT) {
        int d = edge_dst(ei, e);
        int pos = atomicAdd(&cur[d], 1);
        sorted[indptr[d] + pos] = e;
    }
}

// ---------------------------------------------------------------------------
// fp32 tiled GEMM: C[M,Nn] = A[M,K] @ B[K,Nn] (+bias)(+relu)
// 128x128 block tile, BK=8, 256 threads, 8x8 microtile (cols split 4+4 to
// keep LDS reads at 2-way bank aliasing = free).
// Requires Nn % 128 == 0, K % 8 == 0 (true for 2048/256 and 768/2048/256).
// ---------------------------------------------------------------------------
template <int ACT>   // 0 = none, 1 = relu
__global__ __launch_bounds__(256) void gemm_kernel(
    const float* __restrict__ A, const float* __restrict__ B,
    const float* __restrict__ bias, float* __restrict__ C,
    int M, int K, int Nn)
{
    __shared__ float As[8][132];   // [k][m], padded
    __shared__ float Bs[8][132];   // [k][n], padded

    int tid = threadIdx.x;
    int tx = tid & 15, ty = tid >> 4;
    int row0 = blockIdx.y * 128, col0 = blockIdx.x * 128;

    // global-load assignments
    int ar = tid >> 1;            // 0..127 (A row in tile)
    int aq = (tid & 1) * 4;       // 0 or 4 (k offset)
    int br = tid >> 5;            // 0..7   (B k-row)
    int bc = (tid & 31) * 4;      // 0..124 (B col)
    const float* Ap = A + (size_t)(row0 + ar) * K + aq;
    const float* Bp = B + (size_t)br * Nn + col0 + bc;
    bool aok = (row0 + ar) < M;

    float acc[8][8] = {};

    for (int kt = 0; kt < K; kt += 8) {
        float4 av = aok ? *(const float4*)(Ap + kt) : make_float4(0.f, 0.f, 0.f, 0.f);
        float4 bv = *(const float4*)(Bp + (size_t)kt * Nn);
        __syncthreads();          // previous iteration's LDS reads done
        As[aq + 0][ar] = av.x; As[aq + 1][ar] = av.y;
        As[aq + 2][ar] = av.z; As[aq + 3][ar] = av.w;
        *(float4*)&Bs[br][bc] = bv;
        __syncthreads();
#pragma unroll
        for (int kk = 0; kk < 8; kk++) {
            const float4 a0 = *(const float4*)&As[kk][ty * 8];
            const float4 a1 = *(const float4*)&As[kk][ty * 8 + 4];
            const float4 b0 = *(const float4*)&Bs[kk][tx * 4];
            const float4 b1 = *(const float4*)&Bs[kk][64 + tx * 4];
            float av8[8] = {a0.x, a0.y, a0.z, a0.w, a1.x, a1.y, a1.z, a1.w};
            float bv8[8] = {b0.x, b0.y, b0.z, b0.w, b1.x, b1.y, b1.z, b1.w};
#pragma unroll
            for (int i = 0; i < 8; i++)
#pragma unroll
                for (int j = 0; j < 8; j++)
                    acc[i][j] = fmaf(av8[i], bv8[j], acc[i][j]);
        }
    }

    // epilogue: thread covers cols [tx*4, tx*4+4) and [64+tx*4, 64+tx*4+4)
#pragma unroll
    for (int i = 0; i < 8; i++) {
        int r = row0 + ty * 8 + i;
        if (r >= M) continue;
        float out8[8];
#pragma unroll
        for (int j = 0; j < 8; j++) {
            int cc = (j < 4) ? (tx * 4 + j) : (64 + tx * 4 + (j - 4));
            float v = acc[i][j];
            if (bias) v += bias[col0 + cc];
            if (ACT == 1) v = fmaxf(v, 0.f);
            out8[j] = v;
        }
        float* cp = C + (size_t)r * Nn + col0;
        *(float4*)(cp + tx * 4)      = make_float4(out8[0], out8[1], out8[2], out8[3]);
        *(float4*)(cp + 64 + tx * 4) = make_float4(out8[4], out8[5], out8[6], out8[7]);
    }
}

// ---------------------------------------------------------------------------
// per-node attention coefficients: as[n,h] = <H[n,h,:], a_src[h,:]> (and dst)
// one block per node, 32 lanes per head
// ---------------------------------------------------------------------------
__global__ __launch_bounds__(256) void attn_kernel(
    const float* __restrict__ H, const float* __restrict__ a_src,
    const float* __restrict__ a_dst, float* __restrict__ as_out,
    float* __restrict__ ad_out)
{
    int n = blockIdx.x;
    int t = threadIdx.x;
    int h = t >> 5, l = t & 31;
    const float* hp  = H + (size_t)n * HC + h * HID;
    const float* asp = a_src + h * HID;
    const float* adp = a_dst + h * HID;
    float sa = 0.f, sd = 0.f;
#pragma unroll
    for (int k = 0; k < HID / 32; k++) {
        int c = l + k * 32;
        float v = hp[c];
        sa += v * asp[c];
        sd += v * adp[c];
    }
#pragma unroll
    for (int o = 16; o > 0; o >>= 1) {
        sa += __shfl_xor(sa, o, 32);
        sd += __shfl_xor(sd, o, 32);
    }
    if (l == 0) { as_out[n * HEADS + h] = sa; ad_out[n * HEADS + h] = sd; }
}

// ---------------------------------------------------------------------------
// per-dst-node gather aggregation with online segment softmax.
// MODE 0: out[n, h*256+c] = elu(sum_e alpha*h[src] + b1)     (concat layer)
// MODE 1: out[n, c]       = mean_h(sum_e alpha*h[src]) + b2  (mean layer)
// one block (256 threads) per node; no fp atomics anywhere.
// ---------------------------------------------------------------------------
template <int MODE>
__global__ __launch_bounds__(256) void agg_kernel(
    const float* __restrict__ H, const float* __restrict__ as_,
    const float* __restrict__ ad_, const float* __restrict__ bias,
    const int* __restrict__ indptr, const int* __restrict__ sorted,
    const int* __restrict__ ei, float* __restrict__ out)
{
    __shared__ float m8[HEADS], d8[HEADS], adl[HEADS];
    __shared__ int   srcl[64];
    __shared__ float al[64][HEADS];

    int n = blockIdx.x;
    int t = threadIdx.x;
    int start = indptr[n];
    int deg = indptr[n + 1] - start;      // >= 1 (self loop)

    if (t < HEADS) adl[t] = ad_[n * HEADS + t];
    __syncthreads();

    int h = t >> 5, l = t & 31;
    float adh = adl[h];

    // --- segment max per head ---
    float mx = -1e30f;
    for (int j = l; j < deg; j += 32) {
        int e = sorted[start + j];
        int s = edge_src(ei, e);
        float v = as_[s * HEADS + h] + adh;
        v = (v >= 0.f) ? v : NEG_SLOPE * v;
        mx = fmaxf(mx, v);
    }
#pragma unroll
    for (int o = 16; o > 0; o >>= 1) mx = fmaxf(mx, __shfl_xor(mx, o, 32));

    // --- segment sum of exp per head ---
    float sm = 0.f;
    for (int j = l; j < deg; j += 32) {
        int e = sorted[start + j];
        int s = edge_src(ei, e);
        float v = as_[s * HEADS + h] + adh;
        v = (v >= 0.f) ? v : NEG_SLOPE * v;
        sm += expf(v - mx);
    }
#pragma unroll
    for (int o = 16; o > 0; o >>= 1) sm += __shfl_xor(sm, o, 32);
    if (l == 0) { m8[h] = mx; d8[h] = sm; }

    // --- weighted gather; thread t = channel c ---
    float acc[HEADS] = {};
    int c = t;
    for (int base = 0; base < deg; base += 64) {
        int cntc = min(64, deg - base);
        __syncthreads();                  // also covers m8/d8 on first pass,
                                          // and prior chunk's al/srcl readers
        if (t < cntc) srcl[t] = edge_src(ei, sorted[start + base + t]);
        __syncthreads();
        {
            int j = t & 63, h0 = t >> 6;  // h0 in 0..3, covers h0 and h0+4
            if (j < cntc) {
#pragma unroll
                for (int q = 0; q < 2; q++) {
                    int hh = h0 + q * 4;
                    float v = as_[srcl[j] * HEADS + hh] + adl[hh];
                    v = (v >= 0.f) ? v : NEG_SLOPE * v;
                    al[j][hh] = expf(v - m8[hh]) / (d8[hh] + 1e-16f);
                }
            }
        }
        __syncthreads();
        for (int jj = 0; jj < cntc; jj++) {
            int s = srcl[jj];
            const float* hp = H + (size_t)s * HC + c;
#pragma unroll
            for (int hh = 0; hh < HEADS; hh++)
                acc[hh] = fmaf(al[jj][hh], hp[hh * HID], acc[hh]);
        }
    }

    if (MODE == 0) {
#pragma unroll
        for (int hh = 0; hh < HEADS; hh++) {
            float v = acc[hh] + bias[hh * HID + c];
            v = (v > 0.f) ? v : expm1f(v);          // ELU (alpha=1)
            out[(size_t)n * HC + hh * HID + c] = v;
        }
    } else {
        float s = 0.f;
#pragma unroll
        for (int hh = 0; hh < HEADS; hh++) s += acc[hh];
        out[(size_t)n * HID + c] = s * 0.125f + bias[c];
    }
}

// ---------------------------------------------------------------------------
extern "C" void kernel_launch(void* const* d_in, const int* in_sizes, int n_in,
                              void* d_out, int out_size, void* d_ws, size_t ws_size,
                              hipStream_t stream)
{
    const float* x      = (const float*)d_in[0];
    const int*   ei     = (const int*)  d_in[1];
    const float* W1     = (const float*)d_in[2];
    const float* a_src1 = (const float*)d_in[3];
    const float* a_dst1 = (const float*)d_in[4];
    const float* b1     = (const float*)d_in[5];
    const float* W2     = (const float*)d_in[6];
    const float* a_src2 = (const float*)d_in[7];
    const float* a_dst2 = (const float*)d_in[8];
    const float* b2     = (const float*)d_in[9];
    const float* Wp     = (const float*)d_in[10];
    const float* bp     = (const float*)d_in[11];
    float* out = (float*)d_out;

    char* ws = (char*)d_ws;
    size_t off = 0;
    auto alloc = [&](size_t bytes) -> char* {
        char* p = ws + off;
        off += (bytes + 255) & ~(size_t)255;
        return p;
    };
    float* bufA   = (float*)alloc((size_t)NNODES * HC * sizeof(float));   // 81.9 MB
    float* bufB   = (float*)alloc((size_t)NNODES * HC * sizeof(float));   // 81.9 MB
    float* as_    = (float*)alloc((size_t)NNODES * HEADS * sizeof(float));
    float* ad_    = (float*)alloc((size_t)NNODES * HEADS * sizeof(float));
    int*   cnt    = (int*)  alloc((size_t)NNODES * sizeof(int));
    int*   cur    = (int*)  alloc((size_t)NNODES * sizeof(int));
    int*   indptr = (int*)  alloc((size_t)(NNODES + 1) * sizeof(int));
    int*   sorted = (int*)  alloc((size_t)E_TOT * sizeof(int));
    float* out2   = (float*)alloc((size_t)NNODES * HID * sizeof(float));  // 10.2 MB

    // --- CSR build (cheap; depends only on edge_index, redone every call) ---
    hipMemsetAsync(cnt, 0, NNODES * sizeof(int), stream);
    hipMemsetAsync(cur, 0, NNODES * sizeof(int), stream);
    count_kernel<<<(E_TOT + 255) / 256, 256, 0, stream>>>(ei, cnt);
    scan_kernel<<<1, 1024, 0, stream>>>(cnt, indptr);
    scatter_kernel<<<(E_TOT + 255) / 256, 256, 0, stream>>>(ei, indptr, cur, sorted);

    dim3 gBig(HC / 128, (NNODES + 127) / 128);   // 16 x 79

    // Layer 1: H1 = x @ W1  (b1 applied post-aggregation, per reference)
    gemm_kernel<0><<<gBig, 256, 0, stream>>>(x, W1, nullptr, bufA, NNODES, IN_DIM, HC);
    attn_kernel<<<NNODES, 256, 0, stream>>>(bufA, a_src1, a_dst1, as_, ad_);
    agg_kernel<0><<<NNODES, 256, 0, stream>>>(bufA, as_, ad_, b1, indptr, sorted, ei, bufB);

    // Layer 2: H2 = elu_agg @ W2 ; mean over heads + b2
    gemm_kernel<0><<<gBig, 256, 0, stream>>>(bufB, W2, nullptr, bufA, NNODES, HC, HC);
    attn_kernel<<<NNODES, 256, 0, stream>>>(bufA, a_src2, a_dst2, as_, ad_);
    agg_kernel<1><<<NNODES, 256, 0, stream>>>(bufA, as_, ad_, b2, indptr, sorted, ei, out2);

    // Projection + ReLU
    dim3 gProj(HID / 128, (NNODES + 127) / 128); // 2 x 79
    gemm_kernel<1><<<gProj, 256, 0, stream>>>(out2, Wp, bp, out, NNODES, HID, HID);
}

// Round 2
// 784.740 us; speedup vs baseline: 2.2399x; 2.2399x over previous
//
#include <hip/hip_runtime.h>
#include <cstdint>
#include <cstddef>

#define IN_DIM  768
#define NNODES  10000
#define MPAD    10112        // 79 * 128
#define NEDGES  80000
#define E_TOT   90000        // edges + self loops
#define HEADS   8
#define HID     256
#define HC      2048         // HEADS*HID
#define NEG_SLOPE 0.2f

typedef __attribute__((ext_vector_type(8))) short bf16x8;
typedef __attribute__((ext_vector_type(4))) float f32x4;

// ---------------------------------------------------------------------------
// fp32 -> bf16 split helpers (RNE)
// ---------------------------------------------------------------------------
__device__ __forceinline__ unsigned short f2b(float f) {
    union { float f; uint32_t u; } x; x.f = f;
    uint32_t u = x.u;
    uint32_t r = (u + 0x7fffu + ((u >> 16) & 1u)) >> 16;
    return (unsigned short)r;
}
__device__ __forceinline__ float b2f(unsigned short b) {
    union { uint32_t u; float f; } x; x.u = ((uint32_t)b) << 16;
    return x.f;
}

// ---------------------------------------------------------------------------
// edge helpers: edge ids [0,NEDGES) are real edges, [NEDGES,E_TOT) self loops
// ---------------------------------------------------------------------------
__device__ __forceinline__ int edge_src(const int* __restrict__ ei, int e) {
    return (e < NEDGES) ? ei[e] : (e - NEDGES);
}
__device__ __forceinline__ int edge_dst(const int* __restrict__ ei, int e) {
    return (e < NEDGES) ? ei[NEDGES + e] : (e - NEDGES);
}

// ---------------------------------------------------------------------------
// CSR build: count -> scan -> scatter (int atomics only; fp path is gather)
// ---------------------------------------------------------------------------
__global__ void count_kernel(const int* __restrict__ ei, int* __restrict__ cnt) {
    int e = blockIdx.x * 256 + threadIdx.x;
    if (e < E_TOT) atomicAdd(&cnt[edge_dst(ei, e)], 1);
}

__global__ void scan_kernel(const int* __restrict__ cnt, int* __restrict__ indptr) {
    __shared__ int sums[1024];
    const int CH = 10;
    int t = threadIdx.x;
    int base = t * CH;
    int s = 0;
#pragma unroll
    for (int i = 0; i < CH; i++) { int idx = base + i; if (idx < NNODES) s += cnt[idx]; }
    sums[t] = s;
    __syncthreads();
    for (int off = 1; off < 1024; off <<= 1) {
        int v = (t >= off) ? sums[t - off] : 0;
        __syncthreads();
        sums[t] += v;
        __syncthreads();
    }
    int run = (t == 0) ? 0 : sums[t - 1];
#pragma unroll
    for (int i = 0; i < CH; i++) {
        int idx = base + i;
        if (idx < NNODES) { indptr[idx] = run; run += cnt[idx]; }
    }
    if (t == 0) indptr[NNODES] = E_TOT;
}

__global__ void scatter_kernel(const int* __restrict__ ei, const int* __restrict__ indptr,
                               int* __restrict__ cur, int* __restrict__ sorted) {
    int e = blockIdx.x * 256 + threadIdx.x;
    if (e < E_TOT) {
        int d = edge_dst(ei, e);
        int pos = atomicAdd(&cur[d], 1);
        sorted[indptr[d] + pos] = e;
    }
}

// ---------------------------------------------------------------------------
// split x [rows, cols] fp32 -> hi/lo bf16 [prows, cols], zero-padded rows
// ---------------------------------------------------------------------------
__global__ void split_kernel(const float* __restrict__ src,
                             unsigned short* __restrict__ hi,
                             unsigned short* __restrict__ lo,
                             int rows, int cols, int prows) {
    int i = blockIdx.x * 256 + threadIdx.x;
    int total = (prows * cols) >> 2;
    if (i >= total) return;
    size_t e = (size_t)i * 4;
    int r = (int)(e / cols);
    float4 v = (r < rows) ? *(const float4*)(src + e) : make_float4(0.f, 0.f, 0.f, 0.f);
    float vv[4] = {v.x, v.y, v.z, v.w};
    ushort4 h, l;
    unsigned short* hp = (unsigned short*)&h;
    unsigned short* lp = (unsigned short*)&l;
#pragma unroll
    for (int q = 0; q < 4; q++) {
        unsigned short hb = f2b(vv[q]);
        hp[q] = hb;
        lp[q] = f2b(vv[q] - b2f(hb));
    }
    *(ushort4*)(hi + e) = h;
    *(ushort4*)(lo + e) = l;
}

// ---------------------------------------------------------------------------
// transpose + split: W [K, N] fp32 -> Wt_hi/lo [N, K] bf16.  block (32,8)
// ---------------------------------------------------------------------------
__global__ __launch_bounds__(256) void tsplit_kernel(
    const float* __restrict__ W, unsigned short* __restrict__ th,
    unsigned short* __restrict__ tl, int K, int N) {
    __shared__ float tile[32][33];
    int tx = threadIdx.x, ty = threadIdx.y;
    int bx = blockIdx.x, by = blockIdx.y;   // bx over N tiles, by over K tiles
#pragma unroll
    for (int q = 0; q < 4; q++)
        tile[ty + q * 8][tx] = W[(size_t)(by * 32 + ty + q * 8) * N + bx * 32 + tx];
    __syncthreads();
#pragma unroll
    for (int q = 0; q < 4; q++) {
        float v = tile[tx][ty + q * 8];
        unsigned short hb = f2b(v);
        size_t o = (size_t)(bx * 32 + ty + q * 8) * K + by * 32 + tx;
        th[o] = hb;
        tl[o] = f2b(v - b2f(hb));
    }
}

// zero pad rows [NNODES, MPAD) of the layer-2 activation split buffers
__global__ void zero_tail_kernel(unsigned short* __restrict__ h,
                                 unsigned short* __restrict__ l) {
    int i = blockIdx.x * 256 + threadIdx.x;
    const int total = (MPAD - NNODES) * HC;
    if (i < total) {
        h[(size_t)NNODES * HC + i] = 0;
        l[(size_t)NNODES * HC + i] = 0;
    }
}

// ---------------------------------------------------------------------------
// split-bf16 MFMA GEMM:  C[M,Nn] = (Ah+Al)[Mpad,K] @ (Bh+Bl)[Nn,K]^T
// 128x128 tile, BK=32, 256 threads (4 waves, each 64x64 via 4x4 16x16x32).
// 3-product: ah*bh + al*bh + ah*bl  (al*bl dropped, ~2^-18 relative).
// Staging via global_load_lds width=16 (m97 structure).
// Requires K%32==0, Nn%128==0, grid.y*128 <= Mpad (A rows padded+zeroed).
// ---------------------------------------------------------------------------
__global__ __launch_bounds__(256) void mfma_gemm_kernel(
    const unsigned short* __restrict__ Ah, const unsigned short* __restrict__ Al,
    const unsigned short* __restrict__ Bh, const unsigned short* __restrict__ Bl,
    float* __restrict__ C, int M, int K, int Nn)
{
    __shared__ __align__(16) unsigned short sAh[128 * 32];
    __shared__ __align__(16) unsigned short sAl[128 * 32];
    __shared__ __align__(16) unsigned short sBh[128 * 32];
    __shared__ __align__(16) unsigned short sBl[128 * 32];

    int t = threadIdx.x;
    int row0 = blockIdx.y * 128;
    int col0 = blockIdx.x * 128;

    // staging: slot s covers (m = s>>2, k-offset = (s&3)*8); slot -> lds 16B
    int s0 = t, s1 = t + 256;
    int m0 = s0 >> 2, k0 = (s0 & 3) * 8;
    int m1 = s1 >> 2, k1 = (s1 & 3) * 8;
    const unsigned short* a0h = Ah + (size_t)(row0 + m0) * K + k0;
    const unsigned short* a1h = Ah + (size_t)(row0 + m1) * K + k1;
    const unsigned short* a0l = Al + (size_t)(row0 + m0) * K + k0;
    const unsigned short* a1l = Al + (size_t)(row0 + m1) * K + k1;
    const unsigned short* b0h = Bh + (size_t)(col0 + m0) * K + k0;
    const unsigned short* b1h = Bh + (size_t)(col0 + m1) * K + k1;
    const unsigned short* b0l = Bl + (size_t)(col0 + m0) * K + k0;
    const unsigned short* b1l = Bl + (size_t)(col0 + m1) * K + k1;

    int w = t >> 6, lane = t & 63;
    // wave-uniform LDS bases (8 ushorts = 16B per slot)
    unsigned short* lA0 = &((unsigned short*)sAh)[(w * 64) * 8];
    unsigned short* lA1 = &((unsigned short*)sAh)[(w * 64 + 256) * 8];
    unsigned short* lAl0 = &sAl[(w * 64) * 8];
    unsigned short* lAl1 = &sAl[(w * 64 + 256) * 8];
    unsigned short* lB0 = &sBh[(w * 64) * 8];
    unsigned short* lB1 = &sBh[(w * 64 + 256) * 8];
    unsigned short* lBl0 = &sBl[(w * 64) * 8];
    unsigned short* lBl1 = &sBl[(w * 64 + 256) * 8];

    int wm = (w & 1) * 64, wn = (w >> 1) * 64;
    int fr = lane & 15, quad = lane >> 4;

    f32x4 acc[4][4];
#pragma unroll
    for (int i = 0; i < 4; i++)
#pragma unroll
        for (int j = 0; j < 4; j++) acc[i][j] = {0.f, 0.f, 0.f, 0.f};

    for (int kt = 0; kt < K; kt += 32) {
        __builtin_amdgcn_global_load_lds(
            (const __attribute__((address_space(1))) void*)(a0h + kt),
            (__attribute__((address_space(3))) void*)lA0, 16, 0, 0);
        __builtin_amdgcn_global_load_lds(
            (const __attribute__((address_space(1))) void*)(a1h + kt),
            (__attribute__((address_space(3))) void*)lA1, 16, 0, 0);
        __builtin_amdgcn_global_load_lds(
            (const __attribute__((address_space(1))) void*)(a0l + kt),
            (__attribute__((address_space(3))) void*)lAl0, 16, 0, 0);
        __builtin_amdgcn_global_load_lds(
            (const __attribute__((address_space(1))) void*)(a1l + kt),
            (__attribute__((address_space(3))) void*)lAl1, 16, 0, 0);
        __builtin_amdgcn_global_load_lds(
            (const __attribute__((address_space(1))) void*)(b0h + kt),
            (__attribute__((address_space(3))) void*)lB0, 16, 0, 0);
        __builtin_amdgcn_global_load_lds(
            (const __attribute__((address_space(1))) void*)(b1h + kt),
            (__attribute__((address_space(3))) void*)lB1, 16, 0, 0);
        __builtin_amdgcn_global_load_lds(
            (const __attribute__((address_space(1))) void*)(b0l + kt),
            (__attribute__((address_space(3))) void*)lBl0, 16, 0, 0);
        __builtin_amdgcn_global_load_lds(
            (const __attribute__((address_space(1))) void*)(b1l + kt),
            (__attribute__((address_space(3))) void*)lBl1, 16, 0, 0);
        __syncthreads();   // compiler drains vmcnt before s_barrier

        bf16x8 fah[4], fal[4], fbh[4], fbl[4];
#pragma unroll
        for (int i = 0; i < 4; i++) {
            int ma = (wm + i * 16 + fr) * 32 + quad * 8;
            fah[i] = *(const bf16x8*)&sAh[ma];
            fal[i] = *(const bf16x8*)&sAl[ma];
            int nb = (wn + i * 16 + fr) * 32 + quad * 8;
            fbh[i] = *(const bf16x8*)&sBh[nb];
            fbl[i] = *(const bf16x8*)&sBl[nb];
        }
#pragma unroll
        for (int i = 0; i < 4; i++)
#pragma unroll
            for (int j = 0; j < 4; j++) {
                acc[i][j] = __builtin_amdgcn_mfma_f32_16x16x32_bf16(fah[i], fbh[j], acc[i][j], 0, 0, 0);
                acc[i][j] = __builtin_amdgcn_mfma_f32_16x16x32_bf16(fal[i], fbh[j], acc[i][j], 0, 0, 0);
                acc[i][j] = __builtin_amdgcn_mfma_f32_16x16x32_bf16(fah[i], fbl[j], acc[i][j], 0, 0, 0);
            }
        __syncthreads();
    }

    // C/D layout (measured m89/m91): col = lane&15, row = quad*4 + reg
#pragma unroll
    for (int i = 0; i < 4; i++) {
        int mbase = row0 + wm + i * 16 + quad * 4;
#pragma unroll
        for (int j = 0; j < 4; j++) {
            int n = col0 + wn + j * 16 + fr;
#pragma unroll
            for (int r = 0; r < 4; r++) {
                int m = mbase + r;
                if (m < M) C[(size_t)m * Nn + n] = acc[i][j][r];
            }
        }
    }
}

// ---------------------------------------------------------------------------
// fp32 tiled GEMM (kept for the small 256x256 projection)
// ---------------------------------------------------------------------------
template <int ACT>   // 0 = none, 1 = relu
__global__ __launch_bounds__(256) void gemm_kernel(
    const float* __restrict__ A, const float* __restrict__ B,
    const float* __restrict__ bias, float* __restrict__ C,
    int M, int K, int Nn)
{
    __shared__ float As[8][132];
    __shared__ float Bs[8][132];

    int tid = threadIdx.x;
    int tx = tid & 15, ty = tid >> 4;
    int row0 = blockIdx.y * 128, col0 = blockIdx.x * 128;

    int ar = tid >> 1;
    int aq = (tid & 1) * 4;
    int br = tid >> 5;
    int bc = (tid & 31) * 4;
    const float* Ap = A + (size_t)(row0 + ar) * K + aq;
    const float* Bp = B + (size_t)br * Nn + col0 + bc;
    bool aok = (row0 + ar) < M;

    float acc[8][8] = {};

    for (int kt = 0; kt < K; kt += 8) {
        float4 av = aok ? *(const float4*)(Ap + kt) : make_float4(0.f, 0.f, 0.f, 0.f);
        float4 bv = *(const float4*)(Bp + (size_t)kt * Nn);
        __syncthreads();
        As[aq + 0][ar] = av.x; As[aq + 1][ar] = av.y;
        As[aq + 2][ar] = av.z; As[aq + 3][ar] = av.w;
        *(float4*)&Bs[br][bc] = bv;
        __syncthreads();
#pragma unroll
        for (int kk = 0; kk < 8; kk++) {
            const float4 a0 = *(const float4*)&As[kk][ty * 8];
            const float4 a1 = *(const float4*)&As[kk][ty * 8 + 4];
            const float4 b0 = *(const float4*)&Bs[kk][tx * 4];
            const float4 b1 = *(const float4*)&Bs[kk][64 + tx * 4];
            float av8[8] = {a0.x, a0.y, a0.z, a0.w, a1.x, a1.y, a1.z, a1.w};
            float bv8[8] = {b0.x, b0.y, b0.z, b0.w, b1.x, b1.y, b1.z, b1.w};
#pragma unroll
            for (int i = 0; i < 8; i++)
#pragma unroll
                for (int j = 0; j < 8; j++)
                    acc[i][j] = fmaf(av8[i], bv8[j], acc[i][j]);
        }
    }

#pragma unroll
    for (int i = 0; i < 8; i++) {
        int r = row0 + ty * 8 + i;
        if (r >= M) continue;
        float out8[8];
#pragma unroll
        for (int j = 0; j < 8; j++) {
            int cc = (j < 4) ? (tx * 4 + j) : (64 + tx * 4 + (j - 4));
            float v = acc[i][j];
            if (bias) v += bias[col0 + cc];
            if (ACT == 1) v = fmaxf(v, 0.f);
            out8[j] = v;
        }
        float* cp = C + (size_t)r * Nn + col0;
        *(float4*)(cp + tx * 4)      = make_float4(out8[0], out8[1], out8[2], out8[3]);
        *(float4*)(cp + 64 + tx * 4) = make_float4(out8[4], out8[5], out8[6], out8[7]);
    }
}

// ---------------------------------------------------------------------------
// per-node attention coefficients
// ---------------------------------------------------------------------------
__global__ __launch_bounds__(256) void attn_kernel(
    const float* __restrict__ H, const float* __restrict__ a_src,
    const float* __restrict__ a_dst, float* __restrict__ as_out,
    float* __restrict__ ad_out)
{
    int n = blockIdx.x;
    int t = threadIdx.x;
    int h = t >> 5, l = t & 31;
    const float* hp  = H + (size_t)n * HC + h * HID;
    const float* asp = a_src + h * HID;
    const float* adp = a_dst + h * HID;
    float sa = 0.f, sd = 0.f;
#pragma unroll
    for (int k = 0; k < HID / 32; k++) {
        int c = l + k * 32;
        float v = hp[c];
        sa += v * asp[c];
        sd += v * adp[c];
    }
#pragma unroll
    for (int o = 16; o > 0; o >>= 1) {
        sa += __shfl_xor(sa, o, 32);
        sd += __shfl_xor(sd, o, 32);
    }
    if (l == 0) { as_out[n * HEADS + h] = sa; ad_out[n * HEADS + h] = sd; }
}

// ---------------------------------------------------------------------------
// per-dst-node gather aggregation with segment softmax.
// MODE 0: elu(sum + b1) -> split hi/lo bf16 [MPAD, HC]   (feeds MFMA GEMM2)
// MODE 1: mean over heads + b2 -> fp32 [N, HID]
// ---------------------------------------------------------------------------
template <int MODE>
__global__ __launch_bounds__(256) void agg_kernel(
    const float* __restrict__ H, const float* __restrict__ as_,
    const float* __restrict__ ad_, const float* __restrict__ bias,
    const int* __restrict__ indptr, const int* __restrict__ sorted,
    const int* __restrict__ ei, float* __restrict__ outf,
    unsigned short* __restrict__ outh, unsigned short* __restrict__ outl)
{
    __shared__ float m8[HEADS], d8[HEADS], adl[HEADS];
    __shared__ int   srcl[64];
    __shared__ float al[64][HEADS];

    int n = blockIdx.x;
    int t = threadIdx.x;
    int start = indptr[n];
    int deg = indptr[n + 1] - start;

    if (t < HEADS) adl[t] = ad_[n * HEADS + t];
    __syncthreads();

    int h = t >> 5, l = t & 31;
    float adh = adl[h];

    float mx = -1e30f;
    for (int j = l; j < deg; j += 32) {
        int e = sorted[start + j];
        int s = edge_src(ei, e);
        float v = as_[s * HEADS + h] + adh;
        v = (v >= 0.f) ? v : NEG_SLOPE * v;
        mx = fmaxf(mx, v);
    }
#pragma unroll
    for (int o = 16; o > 0; o >>= 1) mx = fmaxf(mx, __shfl_xor(mx, o, 32));

    float sm = 0.f;
    for (int j = l; j < deg; j += 32) {
        int e = sorted[start + j];
        int s = edge_src(ei, e);
        float v = as_[s * HEADS + h] + adh;
        v = (v >= 0.f) ? v : NEG_SLOPE * v;
        sm += expf(v - mx);
    }
#pragma unroll
    for (int o = 16; o > 0; o >>= 1) sm += __shfl_xor(sm, o, 32);
    if (l == 0) { m8[h] = mx; d8[h] = sm; }

    float acc[HEADS] = {};
    int c = t;
    for (int base = 0; base < deg; base += 64) {
        int cntc = min(64, deg - base);
        __syncthreads();
        if (t < cntc) srcl[t] = edge_src(ei, sorted[start + base + t]);
        __syncthreads();
        {
            int j = t & 63, h0 = t >> 6;
            if (j < cntc) {
#pragma unroll
                for (int q = 0; q < 2; q++) {
                    int hh = h0 + q * 4;
                    float v = as_[srcl[j] * HEADS + hh] + adl[hh];
                    v = (v >= 0.f) ? v : NEG_SLOPE * v;
                    al[j][hh] = expf(v - m8[hh]) / (d8[hh] + 1e-16f);
                }
            }
        }
        __syncthreads();
        for (int jj = 0; jj < cntc; jj++) {
            int s = srcl[jj];
            const float* hp = H + (size_t)s * HC + c;
#pragma unroll
            for (int hh = 0; hh < HEADS; hh++)
                acc[hh] = fmaf(al[jj][hh], hp[hh * HID], acc[hh]);
        }
    }

    if (MODE == 0) {
#pragma unroll
        for (int hh = 0; hh < HEADS; hh++) {
            float v = acc[hh] + bias[hh * HID + c];
            v = (v > 0.f) ? v : expm1f(v);          // ELU (alpha=1)
            unsigned short hb = f2b(v);
            size_t o = (size_t)n * HC + hh * HID + c;
            outh[o] = hb;
            outl[o] = f2b(v - b2f(hb));
        }
    } else {
        float s = 0.f;
#pragma unroll
        for (int hh = 0; hh < HEADS; hh++) s += acc[hh];
        outf[(size_t)n * HID + c] = s * 0.125f + bias[c];
    }
}

// ---------------------------------------------------------------------------
extern "C" void kernel_launch(void* const* d_in, const int* in_sizes, int n_in,
                              void* d_out, int out_size, void* d_ws, size_t ws_size,
                              hipStream_t stream)
{
    const float* x      = (const float*)d_in[0];
    const int*   ei     = (const int*)  d_in[1];
    const float* W1     = (const float*)d_in[2];
    const float* a_src1 = (const float*)d_in[3];
    const float* a_dst1 = (const float*)d_in[4];
    const float* b1     = (const float*)d_in[5];
    const float* W2     = (const float*)d_in[6];
    const float* a_src2 = (const float*)d_in[7];
    const float* a_dst2 = (const float*)d_in[8];
    const float* b2     = (const float*)d_in[9];
    const float* Wp     = (const float*)d_in[10];
    const float* bp     = (const float*)d_in[11];
    float* out = (float*)d_out;

    char* ws = (char*)d_ws;
    size_t off = 0;
    auto alloc = [&](size_t bytes) -> char* {
        char* p = ws + off;
        off += (bytes + 255) & ~(size_t)255;
        return p;
    };
    float* bufA = (float*)alloc((size_t)NNODES * HC * sizeof(float));          // 81.9 MB
    unsigned short* A2h = (unsigned short*)alloc((size_t)MPAD * HC * 2);       // 41.4 MB
    unsigned short* A2l = (unsigned short*)alloc((size_t)MPAD * HC * 2);       // 41.4 MB
    unsigned short* W1th = (unsigned short*)alloc((size_t)HC * IN_DIM * 2);    // 3.1 MB
    unsigned short* W1tl = (unsigned short*)alloc((size_t)HC * IN_DIM * 2);
    unsigned short* W2th = (unsigned short*)alloc((size_t)HC * HC * 2);        // 8.4 MB
    unsigned short* W2tl = (unsigned short*)alloc((size_t)HC * HC * 2);
    float* as_    = (float*)alloc((size_t)NNODES * HEADS * sizeof(float));
    float* ad_    = (float*)alloc((size_t)NNODES * HEADS * sizeof(float));
    int*   cnt    = (int*)  alloc((size_t)NNODES * sizeof(int));
    int*   cur    = (int*)  alloc((size_t)NNODES * sizeof(int));
    int*   indptr = (int*)  alloc((size_t)(NNODES + 1) * sizeof(int));
    int*   sorted = (int*)  alloc((size_t)E_TOT * sizeof(int));
    float* out2   = (float*)alloc((size_t)NNODES * HID * sizeof(float));       // 10.2 MB

    // x split buffers alias A2 (x dead before agg<0> writes A2)
    unsigned short* xh = A2h;   // [MPAD, IN_DIM]
    unsigned short* xl = A2l;

    // --- CSR build ---
    hipMemsetAsync(cnt, 0, NNODES * sizeof(int), stream);
    hipMemsetAsync(cur, 0, NNODES * sizeof(int), stream);
    count_kernel<<<(E_TOT + 255) / 256, 256, 0, stream>>>(ei, cnt);
    scan_kernel<<<1, 1024, 0, stream>>>(cnt, indptr);
    scatter_kernel<<<(E_TOT + 255) / 256, 256, 0, stream>>>(ei, indptr, cur, sorted);

    // --- preprocessing: splits + weight transposes ---
    split_kernel<<<(MPAD * IN_DIM / 4 + 255) / 256, 256, 0, stream>>>(
        x, xh, xl, NNODES, IN_DIM, MPAD);
    dim3 tb(32, 8);
    tsplit_kernel<<<dim3(HC / 32, IN_DIM / 32), tb, 0, stream>>>(W1, W1th, W1tl, IN_DIM, HC);
    tsplit_kernel<<<dim3(HC / 32, HC / 32), tb, 0, stream>>>(W2, W2th, W2tl, HC, HC);

    dim3 gMf(HC / 128, MPAD / 128);   // 16 x 79

    // Layer 1: H1 = x @ W1 (MFMA split-bf16)
    mfma_gemm_kernel<<<gMf, 256, 0, stream>>>(xh, xl, W1th, W1tl, bufA, NNODES, IN_DIM, HC);
    attn_kernel<<<NNODES, 256, 0, stream>>>(bufA, a_src1, a_dst1, as_, ad_);
    agg_kernel<0><<<NNODES, 256, 0, stream>>>(bufA, as_, ad_, b1, indptr, sorted, ei,
                                              nullptr, A2h, A2l);
    zero_tail_kernel<<<((MPAD - NNODES) * HC + 255) / 256, 256, 0, stream>>>(A2h, A2l);

    // Layer 2: H2 = elu_agg @ W2 (MFMA split-bf16)
    mfma_gemm_kernel<<<gMf, 256, 0, stream>>>(A2h, A2l, W2th, W2tl, bufA, NNODES, HC, HC);
    attn_kernel<<<NNODES, 256, 0, stream>>>(bufA, a_src2, a_dst2, as_, ad_);
    agg_kernel<1><<<NNODES, 256, 0, stream>>>(bufA, as_, ad_, b2, indptr, sorted, ei,
                                              out2, nullptr, nullptr);

    // Projection + ReLU (fp32, small)
    dim3 gProj(HID / 128, (NNODES + 127) / 128);
    gemm_kernel<1><<<gProj, 256, 0, stream>>>(out2, Wp, bp, out, NNODES, HID, HID);
}

// Round 3
// 621.338 us; speedup vs baseline: 2.8290x; 1.2630x over previous
//
#include <hip/hip_runtime.h>
#include <cstdint>
#include <cstddef>

#define IN_DIM  768
#define NNODES  10000
#define MPAD    10112        // 79 * 128
#define NEDGES  80000
#define E_TOT   90000        // edges + self loops
#define HEADS   8
#define HID     256
#define HC      2048         // HEADS*HID
#define NEG_SLOPE 0.2f

typedef _Float16 __attribute__((ext_vector_type(8))) f16x8;
typedef float    __attribute__((ext_vector_type(4))) f32x4;

// ---------------------------------------------------------------------------
// edge helpers: edge ids [0,NEDGES) are real edges, [NEDGES,E_TOT) self loops
// ---------------------------------------------------------------------------
__device__ __forceinline__ int edge_src(const int* __restrict__ ei, int e) {
    return (e < NEDGES) ? ei[e] : (e - NEDGES);
}
__device__ __forceinline__ int edge_dst(const int* __restrict__ ei, int e) {
    return (e < NEDGES) ? ei[NEDGES + e] : (e - NEDGES);
}

// ---------------------------------------------------------------------------
// CSR build: count -> scan -> scatter (int atomics only; fp path is gather)
// ---------------------------------------------------------------------------
__global__ void count_kernel(const int* __restrict__ ei, int* __restrict__ cnt) {
    int e = blockIdx.x * 256 + threadIdx.x;
    if (e < E_TOT) atomicAdd(&cnt[edge_dst(ei, e)], 1);
}

__global__ void scan_kernel(const int* __restrict__ cnt, int* __restrict__ indptr) {
    __shared__ int sums[1024];
    const int CH = 10;
    int t = threadIdx.x;
    int base = t * CH;
    int s = 0;
#pragma unroll
    for (int i = 0; i < CH; i++) { int idx = base + i; if (idx < NNODES) s += cnt[idx]; }
    sums[t] = s;
    __syncthreads();
    for (int off = 1; off < 1024; off <<= 1) {
        int v = (t >= off) ? sums[t - off] : 0;
        __syncthreads();
        sums[t] += v;
        __syncthreads();
    }
    int run = (t == 0) ? 0 : sums[t - 1];
#pragma unroll
    for (int i = 0; i < CH; i++) {
        int idx = base + i;
        if (idx < NNODES) { indptr[idx] = run; run += cnt[idx]; }
    }
    if (t == 0) indptr[NNODES] = E_TOT;
}

__global__ void scatter_kernel(const int* __restrict__ ei, const int* __restrict__ indptr,
                               int* __restrict__ cur, int* __restrict__ sorted) {
    int e = blockIdx.x * 256 + threadIdx.x;
    if (e < E_TOT) {
        int d = edge_dst(ei, e);
        int pos = atomicAdd(&cur[d], 1);
        sorted[indptr[d] + pos] = e;
    }
}

// ---------------------------------------------------------------------------
// convert x [rows, cols] fp32 -> fp16 [prows, cols], zero-padded rows
// ---------------------------------------------------------------------------
__global__ void cvt_kernel(const float* __restrict__ src,
                           _Float16* __restrict__ dst,
                           int rows, int cols, int prows) {
    int i = blockIdx.x * 256 + threadIdx.x;
    int total = (prows * cols) >> 2;
    if (i >= total) return;
    size_t e = (size_t)i * 4;
    int r = (int)(e / cols);
    float4 v = (r < rows) ? *(const float4*)(src + e) : make_float4(0.f, 0.f, 0.f, 0.f);
    _Float16 h4[4] = {(_Float16)v.x, (_Float16)v.y, (_Float16)v.z, (_Float16)v.w};
    *(ushort4*)(dst + e) = *(ushort4*)h4;
}

// ---------------------------------------------------------------------------
// transpose + convert: W [K, N] fp32 -> Wt [N, K] fp16.  block (32,8)
// ---------------------------------------------------------------------------
__global__ __launch_bounds__(256) void tcvt_kernel(
    const float* __restrict__ W, _Float16* __restrict__ T, int K, int N) {
    __shared__ float tile[32][33];
    int tx = threadIdx.x, ty = threadIdx.y;
    int bx = blockIdx.x, by = blockIdx.y;   // bx over N tiles, by over K tiles
#pragma unroll
    for (int q = 0; q < 4; q++)
        tile[ty + q * 8][tx] = W[(size_t)(by * 32 + ty + q * 8) * N + bx * 32 + tx];
    __syncthreads();
#pragma unroll
    for (int q = 0; q < 4; q++) {
        float v = tile[tx][ty + q * 8];
        T[(size_t)(bx * 32 + ty + q * 8) * K + by * 32 + tx] = (_Float16)v;
    }
}

// zero pad rows [NNODES, MPAD) of the layer-2 fp16 activation buffer
__global__ void zero_tail_kernel(_Float16* __restrict__ h) {
    int i = blockIdx.x * 256 + threadIdx.x;
    const int total = (MPAD - NNODES) * HC;
    if (i < total) h[(size_t)NNODES * HC + i] = (_Float16)0.f;
}

// ---------------------------------------------------------------------------
// fp16 MFMA GEMM:  C[M,Nn] = A[Mpad,K] @ B[Nn,K]^T   (m97 structure)
// 128x128 tile, BK=32, 256 threads (4 waves, each 64x64 via 4x4 16x16x32).
// Staging via global_load_lds width=16.
// Requires K%32==0, Nn%128==0, grid.y*128 <= Mpad (A rows padded+zeroed).
// ---------------------------------------------------------------------------
__global__ __launch_bounds__(256) void mfma_gemm_kernel(
    const _Float16* __restrict__ A, const _Float16* __restrict__ B,
    float* __restrict__ C, int M, int K, int Nn)
{
    __shared__ __align__(16) _Float16 sA[128 * 32];
    __shared__ __align__(16) _Float16 sB[128 * 32];

    int t = threadIdx.x;
    int row0 = blockIdx.y * 128;
    int col0 = blockIdx.x * 128;

    // staging: slot s covers (m = s>>2, k-offset = (s&3)*8); each slot = 16B
    int s0 = t, s1 = t + 256;
    int m0 = s0 >> 2, k0 = (s0 & 3) * 8;
    int m1 = s1 >> 2, k1 = (s1 & 3) * 8;
    const _Float16* a0 = A + (size_t)(row0 + m0) * K + k0;
    const _Float16* a1 = A + (size_t)(row0 + m1) * K + k1;
    const _Float16* b0 = B + (size_t)(col0 + m0) * K + k0;
    const _Float16* b1 = B + (size_t)(col0 + m1) * K + k1;

    int w = t >> 6, lane = t & 63;
    // wave-uniform LDS bases (8 halves = 16B per slot)
    _Float16* lA0 = &sA[(w * 64) * 8];
    _Float16* lA1 = &sA[(w * 64 + 256) * 8];
    _Float16* lB0 = &sB[(w * 64) * 8];
    _Float16* lB1 = &sB[(w * 64 + 256) * 8];

    int wm = (w & 1) * 64, wn = (w >> 1) * 64;
    int fr = lane & 15, quad = lane >> 4;

    f32x4 acc[4][4];
#pragma unroll
    for (int i = 0; i < 4; i++)
#pragma unroll
        for (int j = 0; j < 4; j++) acc[i][j] = {0.f, 0.f, 0.f, 0.f};

    for (int kt = 0; kt < K; kt += 32) {
        __builtin_amdgcn_global_load_lds(
            (const __attribute__((address_space(1))) void*)(a0 + kt),
            (__attribute__((address_space(3))) void*)lA0, 16, 0, 0);
        __builtin_amdgcn_global_load_lds(
            (const __attribute__((address_space(1))) void*)(a1 + kt),
            (__attribute__((address_space(3))) void*)lA1, 16, 0, 0);
        __builtin_amdgcn_global_load_lds(
            (const __attribute__((address_space(1))) void*)(b0 + kt),
            (__attribute__((address_space(3))) void*)lB0, 16, 0, 0);
        __builtin_amdgcn_global_load_lds(
            (const __attribute__((address_space(1))) void*)(b1 + kt),
            (__attribute__((address_space(3))) void*)lB1, 16, 0, 0);
        __syncthreads();   // compiler drains vmcnt before s_barrier

        f16x8 fa[4], fb[4];
#pragma unroll
        for (int i = 0; i < 4; i++) {
            fa[i] = *(const f16x8*)&sA[(wm + i * 16 + fr) * 32 + quad * 8];
            fb[i] = *(const f16x8*)&sB[(wn + i * 16 + fr) * 32 + quad * 8];
        }
#pragma unroll
        for (int i = 0; i < 4; i++)
#pragma unroll
            for (int j = 0; j < 4; j++)
                acc[i][j] = __builtin_amdgcn_mfma_f32_16x16x32_f16(fa[i], fb[j], acc[i][j], 0, 0, 0);
        __syncthreads();
    }

    // C/D layout (measured m89/m91): col = lane&15, row = quad*4 + reg
#pragma unroll
    for (int i = 0; i < 4; i++) {
        int mbase = row0 + wm + i * 16 + quad * 4;
#pragma unroll
        for (int j = 0; j < 4; j++) {
            int n = col0 + wn + j * 16 + fr;
#pragma unroll
            for (int r = 0; r < 4; r++) {
                int m = mbase + r;
                if (m < M) C[(size_t)m * Nn + n] = acc[i][j][r];
            }
        }
    }
}

// ---------------------------------------------------------------------------
// fp32 tiled GEMM (kept for the small 256x256 projection)
// ---------------------------------------------------------------------------
template <int ACT>   // 0 = none, 1 = relu
__global__ __launch_bounds__(256) void gemm_kernel(
    const float* __restrict__ A, const float* __restrict__ B,
    const float* __restrict__ bias, float* __restrict__ C,
    int M, int K, int Nn)
{
    __shared__ float As[8][132];
    __shared__ float Bs[8][132];

    int tid = threadIdx.x;
    int tx = tid & 15, ty = tid >> 4;
    int row0 = blockIdx.y * 128, col0 = blockIdx.x * 128;

    int ar = tid >> 1;
    int aq = (tid & 1) * 4;
    int br = tid >> 5;
    int bc = (tid & 31) * 4;
    const float* Ap = A + (size_t)(row0 + ar) * K + aq;
    const float* Bp = B + (size_t)br * Nn + col0 + bc;
    bool aok = (row0 + ar) < M;

    float acc[8][8] = {};

    for (int kt = 0; kt < K; kt += 8) {
        float4 av = aok ? *(const float4*)(Ap + kt) : make_float4(0.f, 0.f, 0.f, 0.f);
        float4 bv = *(const float4*)(Bp + (size_t)kt * Nn);
        __syncthreads();
        As[aq + 0][ar] = av.x; As[aq + 1][ar] = av.y;
        As[aq + 2][ar] = av.z; As[aq + 3][ar] = av.w;
        *(float4*)&Bs[br][bc] = bv;
        __syncthreads();
#pragma unroll
        for (int kk = 0; kk < 8; kk++) {
            const float4 a0 = *(const float4*)&As[kk][ty * 8];
            const float4 a1 = *(const float4*)&As[kk][ty * 8 + 4];
            const float4 b0 = *(const float4*)&Bs[kk][tx * 4];
            const float4 b1 = *(const float4*)&Bs[kk][64 + tx * 4];
            float av8[8] = {a0.x, a0.y, a0.z, a0.w, a1.x, a1.y, a1.z, a1.w};
            float bv8[8] = {b0.x, b0.y, b0.z, b0.w, b1.x, b1.y, b1.z, b1.w};
#pragma unroll
            for (int i = 0; i < 8; i++)
#pragma unroll
                for (int j = 0; j < 8; j++)
                    acc[i][j] = fmaf(av8[i], bv8[j], acc[i][j]);
        }
    }

#pragma unroll
    for (int i = 0; i < 8; i++) {
        int r = row0 + ty * 8 + i;
        if (r >= M) continue;
        float out8[8];
#pragma unroll
        for (int j = 0; j < 8; j++) {
            int cc = (j < 4) ? (tx * 4 + j) : (64 + tx * 4 + (j - 4));
            float v = acc[i][j];
            if (bias) v += bias[col0 + cc];
            if (ACT == 1) v = fmaxf(v, 0.f);
            out8[j] = v;
        }
        float* cp = C + (size_t)r * Nn + col0;
        *(float4*)(cp + tx * 4)      = make_float4(out8[0], out8[1], out8[2], out8[3]);
        *(float4*)(cp + 64 + tx * 4) = make_float4(out8[4], out8[5], out8[6], out8[7]);
    }
}

// ---------------------------------------------------------------------------
// per-node attention coefficients
// ---------------------------------------------------------------------------
__global__ __launch_bounds__(256) void attn_kernel(
    const float* __restrict__ H, const float* __restrict__ a_src,
    const float* __restrict__ a_dst, float* __restrict__ as_out,
    float* __restrict__ ad_out)
{
    int n = blockIdx.x;
    int t = threadIdx.x;
    int h = t >> 5, l = t & 31;
    const float* hp  = H + (size_t)n * HC + h * HID;
    const float* asp = a_src + h * HID;
    const float* adp = a_dst + h * HID;
    float sa = 0.f, sd = 0.f;
#pragma unroll
    for (int k = 0; k < HID / 32; k++) {
        int c = l + k * 32;
        float v = hp[c];
        sa += v * asp[c];
        sd += v * adp[c];
    }
#pragma unroll
    for (int o = 16; o > 0; o >>= 1) {
        sa += __shfl_xor(sa, o, 32);
        sd += __shfl_xor(sd, o, 32);
    }
    if (l == 0) { as_out[n * HEADS + h] = sa; ad_out[n * HEADS + h] = sd; }
}

// ---------------------------------------------------------------------------
// per-dst-node gather aggregation with segment softmax.
// MODE 0: elu(sum + b1) -> fp16 [MPAD, HC]   (feeds MFMA GEMM2)
// MODE 1: mean over heads + b2 -> fp32 [N, HID]
// ---------------------------------------------------------------------------
template <int MODE>
__global__ __launch_bounds__(256) void agg_kernel(
    const float* __restrict__ H, const float* __restrict__ as_,
    const float* __restrict__ ad_, const float* __restrict__ bias,
    const int* __restrict__ indptr, const int* __restrict__ sorted,
    const int* __restrict__ ei, float* __restrict__ outf,
    _Float16* __restrict__ outh)
{
    __shared__ float m8[HEADS], d8[HEADS], adl[HEADS];
    __shared__ int   srcl[64];
    __shared__ float al[64][HEADS];

    int n = blockIdx.x;
    int t = threadIdx.x;
    int start = indptr[n];
    int deg = indptr[n + 1] - start;

    if (t < HEADS) adl[t] = ad_[n * HEADS + t];
    __syncthreads();

    int h = t >> 5, l = t & 31;
    float adh = adl[h];

    float mx = -1e30f;
    for (int j = l; j < deg; j += 32) {
        int e = sorted[start + j];
        int s = edge_src(ei, e);
        float v = as_[s * HEADS + h] + adh;
        v = (v >= 0.f) ? v : NEG_SLOPE * v;
        mx = fmaxf(mx, v);
    }
#pragma unroll
    for (int o = 16; o > 0; o >>= 1) mx = fmaxf(mx, __shfl_xor(mx, o, 32));

    float sm = 0.f;
    for (int j = l; j < deg; j += 32) {
        int e = sorted[start + j];
        int s = edge_src(ei, e);
        float v = as_[s * HEADS + h] + adh;
        v = (v >= 0.f) ? v : NEG_SLOPE * v;
        sm += expf(v - mx);
    }
#pragma unroll
    for (int o = 16; o > 0; o >>= 1) sm += __shfl_xor(sm, o, 32);
    if (l == 0) { m8[h] = mx; d8[h] = sm; }

    float acc[HEADS] = {};
    int c = t;
    for (int base = 0; base < deg; base += 64) {
        int cntc = min(64, deg - base);
        __syncthreads();
        if (t < cntc) srcl[t] = edge_src(ei, sorted[start + base + t]);
        __syncthreads();
        {
            int j = t & 63, h0 = t >> 6;
            if (j < cntc) {
#pragma unroll
                for (int q = 0; q < 2; q++) {
                    int hh = h0 + q * 4;
                    float v = as_[srcl[j] * HEADS + hh] + adl[hh];
                    v = (v >= 0.f) ? v : NEG_SLOPE * v;
                    al[j][hh] = expf(v - m8[hh]) / (d8[hh] + 1e-16f);
                }
            }
        }
        __syncthreads();
        for (int jj = 0; jj < cntc; jj++) {
            int s = srcl[jj];
            const float* hp = H + (size_t)s * HC + c;
#pragma unroll
            for (int hh = 0; hh < HEADS; hh++)
                acc[hh] = fmaf(al[jj][hh], hp[hh * HID], acc[hh]);
        }
    }

    if (MODE == 0) {
#pragma unroll
        for (int hh = 0; hh < HEADS; hh++) {
            float v = acc[hh] + bias[hh * HID + c];
            v = (v > 0.f) ? v : expm1f(v);          // ELU (alpha=1)
            outh[(size_t)n * HC + hh * HID + c] = (_Float16)v;
        }
    } else {
        float s = 0.f;
#pragma unroll
        for (int hh = 0; hh < HEADS; hh++) s += acc[hh];
        outf[(size_t)n * HID + c] = s * 0.125f + bias[c];
    }
}

// ---------------------------------------------------------------------------
extern "C" void kernel_launch(void* const* d_in, const int* in_sizes, int n_in,
                              void* d_out, int out_size, void* d_ws, size_t ws_size,
                              hipStream_t stream)
{
    const float* x      = (const float*)d_in[0];
    const int*   ei     = (const int*)  d_in[1];
    const float* W1     = (const float*)d_in[2];
    const float* a_src1 = (const float*)d_in[3];
    const float* a_dst1 = (const float*)d_in[4];
    const float* b1     = (const float*)d_in[5];
    const float* W2     = (const float*)d_in[6];
    const float* a_src2 = (const float*)d_in[7];
    const float* a_dst2 = (const float*)d_in[8];
    const float* b2     = (const float*)d_in[9];
    const float* Wp     = (const float*)d_in[10];
    const float* bp     = (const float*)d_in[11];
    float* out = (float*)d_out;

    char* ws = (char*)d_ws;
    size_t off = 0;
    auto alloc = [&](size_t bytes) -> char* {
        char* p = ws + off;
        off += (bytes + 255) & ~(size_t)255;
        return p;
    };
    float* bufA = (float*)alloc((size_t)NNODES * HC * sizeof(float));    // 81.9 MB
    _Float16* A2  = (_Float16*)alloc((size_t)MPAD * HC * 2);             // 41.4 MB
    _Float16* W1t = (_Float16*)alloc((size_t)HC * IN_DIM * 2);           // 3.1 MB
    _Float16* W2t = (_Float16*)alloc((size_t)HC * HC * 2);               // 8.4 MB
    float* as_    = (float*)alloc((size_t)NNODES * HEADS * sizeof(float));
    float* ad_    = (float*)alloc((size_t)NNODES * HEADS * sizeof(float));
    int*   cnt    = (int*)  alloc((size_t)NNODES * sizeof(int));
    int*   cur    = (int*)  alloc((size_t)NNODES * sizeof(int));
    int*   indptr = (int*)  alloc((size_t)(NNODES + 1) * sizeof(int));
    int*   sorted = (int*)  alloc((size_t)E_TOT * sizeof(int));
    float* out2   = (float*)alloc((size_t)NNODES * HID * sizeof(float)); // 10.2 MB
    _Float16* xh  = (_Float16*)alloc((size_t)MPAD * IN_DIM * 2);         // 15.5 MB

    // --- CSR build ---
    hipMemsetAsync(cnt, 0, NNODES * sizeof(int), stream);
    hipMemsetAsync(cur, 0, NNODES * sizeof(int), stream);
    count_kernel<<<(E_TOT + 255) / 256, 256, 0, stream>>>(ei, cnt);
    scan_kernel<<<1, 1024, 0, stream>>>(cnt, indptr);
    scatter_kernel<<<(E_TOT + 255) / 256, 256, 0, stream>>>(ei, indptr, cur, sorted);

    // --- preprocessing: fp16 conversions + weight transposes ---
    cvt_kernel<<<(MPAD * IN_DIM / 4 + 255) / 256, 256, 0, stream>>>(
        x, xh, NNODES, IN_DIM, MPAD);
    dim3 tb(32, 8);
    tcvt_kernel<<<dim3(HC / 32, IN_DIM / 32), tb, 0, stream>>>(W1, W1t, IN_DIM, HC);
    tcvt_kernel<<<dim3(HC / 32, HC / 32), tb, 0, stream>>>(W2, W2t, HC, HC);

    dim3 gMf(HC / 128, MPAD / 128);   // 16 x 79

    // Layer 1: H1 = x @ W1 (fp16 MFMA)
    mfma_gemm_kernel<<<gMf, 256, 0, stream>>>(xh, W1t, bufA, NNODES, IN_DIM, HC);
    attn_kernel<<<NNODES, 256, 0, stream>>>(bufA, a_src1, a_dst1, as_, ad_);
    agg_kernel<0><<<NNODES, 256, 0, stream>>>(bufA, as_, ad_, b1, indptr, sorted, ei,
                                              nullptr, A2);
    zero_tail_kernel<<<((MPAD - NNODES) * HC + 255) / 256, 256, 0, stream>>>(A2);

    // Layer 2: H2 = elu_agg @ W2 (fp16 MFMA)
    mfma_gemm_kernel<<<gMf, 256, 0, stream>>>(A2, W2t, bufA, NNODES, HC, HC);
    attn_kernel<<<NNODES, 256, 0, stream>>>(bufA, a_src2, a_dst2, as_, ad_);
    agg_kernel<1><<<NNODES, 256, 0, stream>>>(bufA, as_, ad_, b2, indptr, sorted, ei,
                                              out2, nullptr);

    // Projection + ReLU (fp32, small)
    dim3 gProj(HID / 128, (NNODES + 127) / 128);
    gemm_kernel<1><<<gProj, 256, 0, stream>>>(out2, Wp, bp, out, NNODES, HID, HID);
}

// Round 4
// 564.307 us; speedup vs baseline: 3.1149x; 1.1011x over previous
//
#include <hip/hip_runtime.h>
#include <cstdint>
#include <cstddef>

#define IN_DIM  768
#define NNODES  10000
#define MPAD    10112        // 79 * 128
#define NEDGES  80000
#define E_TOT   90000        // edges + self loops
#define HEADS   8
#define HID     256
#define HC      2048         // HEADS*HID
#define NEG_SLOPE 0.2f

typedef _Float16 __attribute__((ext_vector_type(8))) f16x8;
typedef float    __attribute__((ext_vector_type(4))) f32x4;

// ---------------------------------------------------------------------------
// edge helpers: edge ids [0,NEDGES) are real edges, [NEDGES,E_TOT) self loops
// ---------------------------------------------------------------------------
__device__ __forceinline__ int edge_src(const int* __restrict__ ei, int e) {
    return (e < NEDGES) ? ei[e] : (e - NEDGES);
}
__device__ __forceinline__ int edge_dst(const int* __restrict__ ei, int e) {
    return (e < NEDGES) ? ei[NEDGES + e] : (e - NEDGES);
}

// ---------------------------------------------------------------------------
// CSR build: count -> scan -> scatter (int atomics only; fp path is gather)
// ---------------------------------------------------------------------------
__global__ void count_kernel(const int* __restrict__ ei, int* __restrict__ cnt) {
    int e = blockIdx.x * 256 + threadIdx.x;
    if (e < E_TOT) atomicAdd(&cnt[edge_dst(ei, e)], 1);
}

__global__ void scan_kernel(const int* __restrict__ cnt, int* __restrict__ indptr) {
    __shared__ int sums[1024];
    const int CH = 10;
    int t = threadIdx.x;
    int base = t * CH;
    int s = 0;
#pragma unroll
    for (int i = 0; i < CH; i++) { int idx = base + i; if (idx < NNODES) s += cnt[idx]; }
    sums[t] = s;
    __syncthreads();
    for (int off = 1; off < 1024; off <<= 1) {
        int v = (t >= off) ? sums[t - off] : 0;
        __syncthreads();
        sums[t] += v;
        __syncthreads();
    }
    int run = (t == 0) ? 0 : sums[t - 1];
#pragma unroll
    for (int i = 0; i < CH; i++) {
        int idx = base + i;
        if (idx < NNODES) { indptr[idx] = run; run += cnt[idx]; }
    }
    if (t == 0) indptr[NNODES] = E_TOT;
}

__global__ void scatter_kernel(const int* __restrict__ ei, const int* __restrict__ indptr,
                               int* __restrict__ cur, int* __restrict__ sorted) {
    int e = blockIdx.x * 256 + threadIdx.x;
    if (e < E_TOT) {
        int d = edge_dst(ei, e);
        int pos = atomicAdd(&cur[d], 1);
        sorted[indptr[d] + pos] = e;
    }
}

// ---------------------------------------------------------------------------
// convert x [rows, cols] fp32 -> fp16 [prows, cols], zero-padded rows
// ---------------------------------------------------------------------------
__global__ void cvt_kernel(const float* __restrict__ src,
                           _Float16* __restrict__ dst,
                           int rows, int cols, int prows) {
    int i = blockIdx.x * 256 + threadIdx.x;
    int total = (prows * cols) >> 2;
    if (i >= total) return;
    size_t e = (size_t)i * 4;
    int r = (int)(e / cols);
    float4 v = (r < rows) ? *(const float4*)(src + e) : make_float4(0.f, 0.f, 0.f, 0.f);
    _Float16 h4[4] = {(_Float16)v.x, (_Float16)v.y, (_Float16)v.z, (_Float16)v.w};
    *(ushort4*)(dst + e) = *(ushort4*)h4;
}

// ---------------------------------------------------------------------------
// transpose + convert: W [K, N] fp32 -> Wt [N, K] fp16.  block (32,8)
// ---------------------------------------------------------------------------
__global__ __launch_bounds__(256) void tcvt_kernel(
    const float* __restrict__ W, _Float16* __restrict__ T, int K, int N) {
    __shared__ float tile[32][33];
    int tx = threadIdx.x, ty = threadIdx.y;
    int bx = blockIdx.x, by = blockIdx.y;   // bx over N tiles, by over K tiles
#pragma unroll
    for (int q = 0; q < 4; q++)
        tile[ty + q * 8][tx] = W[(size_t)(by * 32 + ty + q * 8) * N + bx * 32 + tx];
    __syncthreads();
#pragma unroll
    for (int q = 0; q < 4; q++) {
        float v = tile[tx][ty + q * 8];
        T[(size_t)(bx * 32 + ty + q * 8) * K + by * 32 + tx] = (_Float16)v;
    }
}

// ---------------------------------------------------------------------------
// fp16 MFMA GEMM + fused attention-coefficient epilogue.
//   C[M,Nn](fp16) = A[Mpad,K] @ B[Nn,K]^T
//   as_out[m,h] += sum_n C[m,n]*a_src[n]   (this block's 128-col slice, one head)
// 128x128 tile, BK=32, 256 threads, global_load_lds width=16 (m97 structure).
// Requires K%32==0, Nn==HC, grid.y*128 <= Mpad (A rows padded+zeroed).
// ---------------------------------------------------------------------------
__global__ __launch_bounds__(256) void mfma_gemm_kernel(
    const _Float16* __restrict__ A, const _Float16* __restrict__ B,
    _Float16* __restrict__ C, const float* __restrict__ a_src,
    const float* __restrict__ a_dst, float* __restrict__ as_out,
    float* __restrict__ ad_out, int M, int K, int Nn)
{
    __shared__ __align__(16) _Float16 sA[128 * 32];
    __shared__ __align__(16) _Float16 sB[128 * 32];

    int t = threadIdx.x;
    int row0 = blockIdx.y * 128;
    int col0 = blockIdx.x * 128;

    // staging: slot s covers (m = s>>2, k-offset = (s&3)*8); each slot = 16B
    int s0 = t, s1 = t + 256;
    int m0 = s0 >> 2, k0 = (s0 & 3) * 8;
    int m1 = s1 >> 2, k1 = (s1 & 3) * 8;
    const _Float16* a0 = A + (size_t)(row0 + m0) * K + k0;
    const _Float16* a1 = A + (size_t)(row0 + m1) * K + k1;
    const _Float16* b0 = B + (size_t)(col0 + m0) * K + k0;
    const _Float16* b1 = B + (size_t)(col0 + m1) * K + k1;

    int w = t >> 6, lane = t & 63;
    _Float16* lA0 = &sA[(w * 64) * 8];
    _Float16* lA1 = &sA[(w * 64 + 256) * 8];
    _Float16* lB0 = &sB[(w * 64) * 8];
    _Float16* lB1 = &sB[(w * 64 + 256) * 8];

    int wm = (w & 1) * 64, wn = (w >> 1) * 64;
    int fr = lane & 15, quad = lane >> 4;

    f32x4 acc[4][4];
#pragma unroll
    for (int i = 0; i < 4; i++)
#pragma unroll
        for (int j = 0; j < 4; j++) acc[i][j] = {0.f, 0.f, 0.f, 0.f};

    for (int kt = 0; kt < K; kt += 32) {
        __builtin_amdgcn_global_load_lds(
            (const __attribute__((address_space(1))) void*)(a0 + kt),
            (__attribute__((address_space(3))) void*)lA0, 16, 0, 0);
        __builtin_amdgcn_global_load_lds(
            (const __attribute__((address_space(1))) void*)(a1 + kt),
            (__attribute__((address_space(3))) void*)lA1, 16, 0, 0);
        __builtin_amdgcn_global_load_lds(
            (const __attribute__((address_space(1))) void*)(b0 + kt),
            (__attribute__((address_space(3))) void*)lB0, 16, 0, 0);
        __builtin_amdgcn_global_load_lds(
            (const __attribute__((address_space(1))) void*)(b1 + kt),
            (__attribute__((address_space(3))) void*)lB1, 16, 0, 0);
        __syncthreads();

        f16x8 fa[4], fb[4];
#pragma unroll
        for (int i = 0; i < 4; i++) {
            fa[i] = *(const f16x8*)&sA[(wm + i * 16 + fr) * 32 + quad * 8];
            fb[i] = *(const f16x8*)&sB[(wn + i * 16 + fr) * 32 + quad * 8];
        }
#pragma unroll
        for (int i = 0; i < 4; i++)
#pragma unroll
            for (int j = 0; j < 4; j++)
                acc[i][j] = __builtin_amdgcn_mfma_f32_16x16x32_f16(fa[i], fb[j], acc[i][j], 0, 0, 0);
        __syncthreads();
    }

    // epilogue: C/D layout col = lane&15, row = quad*4 + reg (m89/m91)
    int h = col0 >> 8;                 // head of this 128-col slice (Nn == HC)
    float asv[4], adv[4];
#pragma unroll
    for (int j = 0; j < 4; j++) {
        int n = col0 + wn + j * 16 + fr;
        asv[j] = a_src[n];
        adv[j] = a_dst[n];
    }
#pragma unroll
    for (int i = 0; i < 4; i++) {
        int mbase = row0 + wm + i * 16 + quad * 4;
#pragma unroll
        for (int r = 0; r < 4; r++) {
            int m = mbase + r;
            bool ok = (m < M);
            float ps = 0.f, pd = 0.f;
#pragma unroll
            for (int j = 0; j < 4; j++) {
                float v = acc[i][j][r];
                ps = fmaf(v, asv[j], ps);
                pd = fmaf(v, adv[j], pd);
                if (ok) C[(size_t)m * Nn + (col0 + wn + j * 16 + fr)] = (_Float16)v;
            }
            // reduce across the 16 fr-lanes of this quad
#pragma unroll
            for (int o = 8; o > 0; o >>= 1) {
                ps += __shfl_xor(ps, o, 16);
                pd += __shfl_xor(pd, o, 16);
            }
            if (ok && fr == 0) {
                atomicAdd(&as_out[m * HEADS + h], ps);
                atomicAdd(&ad_out[m * HEADS + h], pd);
            }
        }
    }
}

// ---------------------------------------------------------------------------
// fp32 tiled GEMM (kept for the small 256x256 projection)
// ---------------------------------------------------------------------------
template <int ACT>   // 0 = none, 1 = relu
__global__ __launch_bounds__(256) void gemm_kernel(
    const float* __restrict__ A, const float* __restrict__ B,
    const float* __restrict__ bias, float* __restrict__ C,
    int M, int K, int Nn)
{
    __shared__ float As[8][132];
    __shared__ float Bs[8][132];

    int tid = threadIdx.x;
    int tx = tid & 15, ty = tid >> 4;
    int row0 = blockIdx.y * 128, col0 = blockIdx.x * 128;

    int ar = tid >> 1;
    int aq = (tid & 1) * 4;
    int br = tid >> 5;
    int bc = (tid & 31) * 4;
    const float* Ap = A + (size_t)(row0 + ar) * K + aq;
    const float* Bp = B + (size_t)br * Nn + col0 + bc;
    bool aok = (row0 + ar) < M;

    float acc[8][8] = {};

    for (int kt = 0; kt < K; kt += 8) {
        float4 av = aok ? *(const float4*)(Ap + kt) : make_float4(0.f, 0.f, 0.f, 0.f);
        float4 bv = *(const float4*)(Bp + (size_t)kt * Nn);
        __syncthreads();
        As[aq + 0][ar] = av.x; As[aq + 1][ar] = av.y;
        As[aq + 2][ar] = av.z; As[aq + 3][ar] = av.w;
        *(float4*)&Bs[br][bc] = bv;
        __syncthreads();
#pragma unroll
        for (int kk = 0; kk < 8; kk++) {
            const float4 a0 = *(const float4*)&As[kk][ty * 8];
            const float4 a1 = *(const float4*)&As[kk][ty * 8 + 4];
            const float4 b0 = *(const float4*)&Bs[kk][tx * 4];
            const float4 b1 = *(const float4*)&Bs[kk][64 + tx * 4];
            float av8[8] = {a0.x, a0.y, a0.z, a0.w, a1.x, a1.y, a1.z, a1.w};
            float bv8[8] = {b0.x, b0.y, b0.z, b0.w, b1.x, b1.y, b1.z, b1.w};
#pragma unroll
            for (int i = 0; i < 8; i++)
#pragma unroll
                for (int j = 0; j < 8; j++)
                    acc[i][j] = fmaf(av8[i], bv8[j], acc[i][j]);
        }
    }

#pragma unroll
    for (int i = 0; i < 8; i++) {
        int r = row0 + ty * 8 + i;
        if (r >= M) continue;
        float out8[8];
#pragma unroll
        for (int j = 0; j < 8; j++) {
            int cc = (j < 4) ? (tx * 4 + j) : (64 + tx * 4 + (j - 4));
            float v = acc[i][j];
            if (bias) v += bias[col0 + cc];
            if (ACT == 1) v = fmaxf(v, 0.f);
            out8[j] = v;
        }
        float* cp = C + (size_t)r * Nn + col0;
        *(float4*)(cp + tx * 4)      = make_float4(out8[0], out8[1], out8[2], out8[3]);
        *(float4*)(cp + 64 + tx * 4) = make_float4(out8[4], out8[5], out8[6], out8[7]);
    }
}

// ---------------------------------------------------------------------------
// per-dst-node gather aggregation with segment softmax.  H is fp16.
// thread t covers 8 consecutive channels of head t>>5 -> one 16B load/edge.
// MODE 0: elu(sum + b1) -> fp16 [MPAD, HC]; blocks n>=NNODES just zero-pad.
// MODE 1: mean over heads + b2 -> fp32 [N, HID]
// ---------------------------------------------------------------------------
template <int MODE>
__global__ __launch_bounds__(256) void agg_kernel(
    const _Float16* __restrict__ H, const float* __restrict__ as_,
    const float* __restrict__ ad_, const float* __restrict__ bias,
    const int* __restrict__ indptr, const int* __restrict__ sorted,
    const int* __restrict__ ei, float* __restrict__ outf,
    _Float16* __restrict__ outh)
{
    __shared__ float m8[HEADS], d8[HEADS], adl[HEADS];
    __shared__ int   srcl[64];
    __shared__ float al[64][HEADS];
    __shared__ float red[HC];          // MODE 1 cross-head reduction

    int n = blockIdx.x;
    int t = threadIdx.x;

    if (MODE == 0 && n >= NNODES) {    // pad rows for the next MFMA GEMM
        _Float16 z8[8] = {};
        *(f16x8*)&outh[(size_t)n * HC + t * 8] = *(f16x8*)z8;
        return;
    }

    int start = indptr[n];
    int deg = indptr[n + 1] - start;

    if (t < HEADS) adl[t] = ad_[n * HEADS + t];
    __syncthreads();

    int h = t >> 5, l = t & 31;
    float adh = adl[h];

    float mx = -1e30f;
    for (int j = l; j < deg; j += 32) {
        int e = sorted[start + j];
        int s = edge_src(ei, e);
        float v = as_[s * HEADS + h] + adh;
        v = (v >= 0.f) ? v : NEG_SLOPE * v;
        mx = fmaxf(mx, v);
    }
#pragma unroll
    for (int o = 16; o > 0; o >>= 1) mx = fmaxf(mx, __shfl_xor(mx, o, 32));

    float sm = 0.f;
    for (int j = l; j < deg; j += 32) {
        int e = sorted[start + j];
        int s = edge_src(ei, e);
        float v = as_[s * HEADS + h] + adh;
        v = (v >= 0.f) ? v : NEG_SLOPE * v;
        sm += expf(v - mx);
    }
#pragma unroll
    for (int o = 16; o > 0; o >>= 1) sm += __shfl_xor(sm, o, 32);
    if (l == 0) { m8[h] = mx; d8[h] = sm; }

    // gather phase: thread t -> head hh, channels c8..c8+7
    int hh = t >> 5, c8 = (t & 31) * 8;
    const size_t hoff = (size_t)hh * HID + c8;
    float acc[8] = {};
    for (int base = 0; base < deg; base += 64) {
        int cntc = min(64, deg - base);
        __syncthreads();
        if (t < cntc) srcl[t] = edge_src(ei, sorted[start + base + t]);
        __syncthreads();
        {
            int j = t & 63, h0 = t >> 6;
            if (j < cntc) {
#pragma unroll
                for (int q = 0; q < 2; q++) {
                    int hx = h0 + q * 4;
                    float v = as_[srcl[j] * HEADS + hx] + adl[hx];
                    v = (v >= 0.f) ? v : NEG_SLOPE * v;
                    al[j][hx] = expf(v - m8[hx]) / (d8[hx] + 1e-16f);
                }
            }
        }
        __syncthreads();
        for (int jj = 0; jj < cntc; jj++) {
            int s = srcl[jj];
            f16x8 hv = *(const f16x8*)&H[(size_t)s * HC + hoff];
            float a = al[jj][hh];
#pragma unroll
            for (int q = 0; q < 8; q++)
                acc[q] = fmaf(a, (float)hv[q], acc[q]);
        }
    }

    if (MODE == 0) {
        _Float16 o8[8];
#pragma unroll
        for (int q = 0; q < 8; q++) {
            float v = acc[q] + bias[hoff + q];
            v = (v > 0.f) ? v : expm1f(v);          // ELU (alpha=1)
            o8[q] = (_Float16)v;
        }
        *(f16x8*)&outh[(size_t)n * HC + hoff] = *(f16x8*)o8;
    } else {
#pragma unroll
        for (int q = 0; q < 8; q++) red[hoff + q] = acc[q];
        __syncthreads();
        float s = 0.f;
#pragma unroll
        for (int h2 = 0; h2 < HEADS; h2++) s += red[h2 * HID + t];
        outf[(size_t)n * HID + t] = s * 0.125f + bias[t];
    }
}

// ---------------------------------------------------------------------------
extern "C" void kernel_launch(void* const* d_in, const int* in_sizes, int n_in,
                              void* d_out, int out_size, void* d_ws, size_t ws_size,
                              hipStream_t stream)
{
    const float* x      = (const float*)d_in[0];
    const int*   ei     = (const int*)  d_in[1];
    const float* W1     = (const float*)d_in[2];
    const float* a_src1 = (const float*)d_in[3];
    const float* a_dst1 = (const float*)d_in[4];
    const float* b1     = (const float*)d_in[5];
    const float* W2     = (const float*)d_in[6];
    const float* a_src2 = (const float*)d_in[7];
    const float* a_dst2 = (const float*)d_in[8];
    const float* b2     = (const float*)d_in[9];
    const float* Wp     = (const float*)d_in[10];
    const float* bp     = (const float*)d_in[11];
    float* out = (float*)d_out;

    char* ws = (char*)d_ws;
    size_t off = 0;
    auto alloc = [&](size_t bytes) -> char* {
        char* p = ws + off;
        off += (bytes + 255) & ~(size_t)255;
        return p;
    };
    _Float16* Hbuf = (_Float16*)alloc((size_t)NNODES * HC * 2);          // 41 MB (H1, then H2)
    _Float16* A2   = (_Float16*)alloc((size_t)MPAD * HC * 2);            // 41.4 MB
    _Float16* W1t  = (_Float16*)alloc((size_t)HC * IN_DIM * 2);          // 3.1 MB
    _Float16* W2t  = (_Float16*)alloc((size_t)HC * HC * 2);              // 8.4 MB
    _Float16* xh   = (_Float16*)alloc((size_t)MPAD * IN_DIM * 2);        // 15.5 MB
    float* asad   = (float*)alloc((size_t)4 * NNODES * HEADS * sizeof(float)); // 1.28 MB
    float* as1 = asad;
    float* ad1 = asad + (size_t)NNODES * HEADS;
    float* as2 = asad + (size_t)2 * NNODES * HEADS;
    float* ad2 = asad + (size_t)3 * NNODES * HEADS;
    int*   cnt    = (int*)  alloc((size_t)NNODES * sizeof(int));
    int*   cur    = (int*)  alloc((size_t)NNODES * sizeof(int));
    int*   indptr = (int*)  alloc((size_t)(NNODES + 1) * sizeof(int));
    int*   sorted = (int*)  alloc((size_t)E_TOT * sizeof(int));
    float* out2   = (float*)alloc((size_t)NNODES * HID * sizeof(float)); // 10.2 MB

    // --- zero accumulators + CSR build ---
    hipMemsetAsync(cnt, 0, NNODES * sizeof(int), stream);
    hipMemsetAsync(cur, 0, NNODES * sizeof(int), stream);
    hipMemsetAsync(asad, 0, (size_t)4 * NNODES * HEADS * sizeof(float), stream);
    count_kernel<<<(E_TOT + 255) / 256, 256, 0, stream>>>(ei, cnt);
    scan_kernel<<<1, 1024, 0, stream>>>(cnt, indptr);
    scatter_kernel<<<(E_TOT + 255) / 256, 256, 0, stream>>>(ei, indptr, cur, sorted);

    // --- preprocessing: fp16 conversions + weight transposes ---
    cvt_kernel<<<(MPAD * IN_DIM / 4 + 255) / 256, 256, 0, stream>>>(
        x, xh, NNODES, IN_DIM, MPAD);
    dim3 tb(32, 8);
    tcvt_kernel<<<dim3(HC / 32, IN_DIM / 32), tb, 0, stream>>>(W1, W1t, IN_DIM, HC);
    tcvt_kernel<<<dim3(HC / 32, HC / 32), tb, 0, stream>>>(W2, W2t, HC, HC);

    dim3 gMf(HC / 128, MPAD / 128);   // 16 x 79

    // Layer 1: H1 = x @ W1 (fp16 MFMA, fused attn coefficients)
    mfma_gemm_kernel<<<gMf, 256, 0, stream>>>(xh, W1t, Hbuf, a_src1, a_dst1,
                                              as1, ad1, NNODES, IN_DIM, HC);
    agg_kernel<0><<<MPAD, 256, 0, stream>>>(Hbuf, as1, ad1, b1, indptr, sorted, ei,
                                            nullptr, A2);

    // Layer 2: H2 = elu_agg @ W2 (fp16 MFMA, fused attn coefficients)
    mfma_gemm_kernel<<<gMf, 256, 0, stream>>>(A2, W2t, Hbuf, a_src2, a_dst2,
                                              as2, ad2, NNODES, HC, HC);
    agg_kernel<1><<<NNODES, 256, 0, stream>>>(Hbuf, as2, ad2, b2, indptr, sorted, ei,
                                              out2, nullptr);

    // Projection + ReLU (fp32, small)
    dim3 gProj(HID / 128, (NNODES + 127) / 128);
    gemm_kernel<1><<<gProj, 256, 0, stream>>>(out2, Wp, bp, out, NNODES, HID, HID);
}

// Round 5
// 515.643 us; speedup vs baseline: 3.4088x; 1.0944x over previous
//
#include <hip/hip_runtime.h>
#include <cstdint>
#include <cstddef>

#define IN_DIM  768
#define NNODES  10000
#define MPAD    10112        // 79 * 128
#define NEDGES  80000
#define E_TOT   90000        // edges + self loops
#define HEADS   8
#define HID     256
#define HC      2048         // HEADS*HID
#define NEG_SLOPE 0.2f

typedef _Float16 __attribute__((ext_vector_type(8))) f16x8;
typedef float    __attribute__((ext_vector_type(4))) f32x4;

// ---------------------------------------------------------------------------
// edge helpers: edge ids [0,NEDGES) are real edges, [NEDGES,E_TOT) self loops
// ---------------------------------------------------------------------------
__device__ __forceinline__ int edge_src(const int* __restrict__ ei, int e) {
    return (e < NEDGES) ? ei[e] : (e - NEDGES);
}
__device__ __forceinline__ int edge_dst(const int* __restrict__ ei, int e) {
    return (e < NEDGES) ? ei[NEDGES + e] : (e - NEDGES);
}

// ---------------------------------------------------------------------------
// CSR build: count -> scan -> scatter (int atomics only; fp path is gather)
// ---------------------------------------------------------------------------
__global__ void count_kernel(const int* __restrict__ ei, int* __restrict__ cnt) {
    int e = blockIdx.x * 256 + threadIdx.x;
    if (e < E_TOT) atomicAdd(&cnt[edge_dst(ei, e)], 1);
}

__global__ void scan_kernel(const int* __restrict__ cnt, int* __restrict__ indptr) {
    __shared__ int sums[1024];
    const int CH = 10;
    int t = threadIdx.x;
    int base = t * CH;
    int s = 0;
#pragma unroll
    for (int i = 0; i < CH; i++) { int idx = base + i; if (idx < NNODES) s += cnt[idx]; }
    sums[t] = s;
    __syncthreads();
    for (int off = 1; off < 1024; off <<= 1) {
        int v = (t >= off) ? sums[t - off] : 0;
        __syncthreads();
        sums[t] += v;
        __syncthreads();
    }
    int run = (t == 0) ? 0 : sums[t - 1];
#pragma unroll
    for (int i = 0; i < CH; i++) {
        int idx = base + i;
        if (idx < NNODES) { indptr[idx] = run; run += cnt[idx]; }
    }
    if (t == 0) indptr[NNODES] = E_TOT;
}

__global__ void scatter_kernel(const int* __restrict__ ei, const int* __restrict__ indptr,
                               int* __restrict__ cur, int* __restrict__ sorted) {
    int e = blockIdx.x * 256 + threadIdx.x;
    if (e < E_TOT) {
        int d = edge_dst(ei, e);
        int pos = atomicAdd(&cur[d], 1);
        sorted[indptr[d] + pos] = e;
    }
}

// ---------------------------------------------------------------------------
// convert x [rows, cols] fp32 -> fp16 [prows, cols], zero-padded rows
// ---------------------------------------------------------------------------
__global__ void cvt_kernel(const float* __restrict__ src,
                           _Float16* __restrict__ dst,
                           int rows, int cols, int prows) {
    int i = blockIdx.x * 256 + threadIdx.x;
    int total = (prows * cols) >> 2;
    if (i >= total) return;
    size_t e = (size_t)i * 4;
    int r = (int)(e / cols);
    float4 v = (r < rows) ? *(const float4*)(src + e) : make_float4(0.f, 0.f, 0.f, 0.f);
    _Float16 h4[4] = {(_Float16)v.x, (_Float16)v.y, (_Float16)v.z, (_Float16)v.w};
    *(ushort4*)(dst + e) = *(ushort4*)h4;
}

// ---------------------------------------------------------------------------
// transpose + convert: W [K, N] fp32 -> Wt [N, K] fp16.  block (32,8)
// ---------------------------------------------------------------------------
__global__ __launch_bounds__(256) void tcvt_kernel(
    const float* __restrict__ W, _Float16* __restrict__ T, int K, int N) {
    __shared__ float tile[32][33];
    int tx = threadIdx.x, ty = threadIdx.y;
    int bx = blockIdx.x, by = blockIdx.y;   // bx over N tiles, by over K tiles
#pragma unroll
    for (int q = 0; q < 4; q++)
        tile[ty + q * 8][tx] = W[(size_t)(by * 32 + ty + q * 8) * N + bx * 32 + tx];
    __syncthreads();
#pragma unroll
    for (int q = 0; q < 4; q++) {
        float v = tile[tx][ty + q * 8];
        T[(size_t)(bx * 32 + ty + q * 8) * K + by * 32 + tx] = (_Float16)v;
    }
}

// ---------------------------------------------------------------------------
// fp16 MFMA GEMM:  C[M,Nn](fp16) = A[Mpad,K] @ B[Nn,K]^T   (clean m97 body)
// 128x128 tile, BK=32, 256 threads, global_load_lds width=16.
// Requires K%32==0, Nn%128==0, grid.y*128 <= Mpad (A rows padded+zeroed).
// ---------------------------------------------------------------------------
__global__ __launch_bounds__(256) void mfma_gemm_kernel(
    const _Float16* __restrict__ A, const _Float16* __restrict__ B,
    _Float16* __restrict__ C, int M, int K, int Nn)
{
    __shared__ __align__(16) _Float16 sA[128 * 32];
    __shared__ __align__(16) _Float16 sB[128 * 32];

    int t = threadIdx.x;
    int row0 = blockIdx.y * 128;
    int col0 = blockIdx.x * 128;

    // staging: slot s covers (m = s>>2, k-offset = (s&3)*8); each slot = 16B
    int s0 = t, s1 = t + 256;
    int m0 = s0 >> 2, k0 = (s0 & 3) * 8;
    int m1 = s1 >> 2, k1 = (s1 & 3) * 8;
    const _Float16* a0 = A + (size_t)(row0 + m0) * K + k0;
    const _Float16* a1 = A + (size_t)(row0 + m1) * K + k1;
    const _Float16* b0 = B + (size_t)(col0 + m0) * K + k0;
    const _Float16* b1 = B + (size_t)(col0 + m1) * K + k1;

    int w = t >> 6, lane = t & 63;
    _Float16* lA0 = &sA[(w * 64) * 8];
    _Float16* lA1 = &sA[(w * 64 + 256) * 8];
    _Float16* lB0 = &sB[(w * 64) * 8];
    _Float16* lB1 = &sB[(w * 64 + 256) * 8];

    int wm = (w & 1) * 64, wn = (w >> 1) * 64;
    int fr = lane & 15, quad = lane >> 4;

    f32x4 acc[4][4];
#pragma unroll
    for (int i = 0; i < 4; i++)
#pragma unroll
        for (int j = 0; j < 4; j++) acc[i][j] = {0.f, 0.f, 0.f, 0.f};

    for (int kt = 0; kt < K; kt += 32) {
        __builtin_amdgcn_global_load_lds(
            (const __attribute__((address_space(1))) void*)(a0 + kt),
            (__attribute__((address_space(3))) void*)lA0, 16, 0, 0);
        __builtin_amdgcn_global_load_lds(
            (const __attribute__((address_space(1))) void*)(a1 + kt),
            (__attribute__((address_space(3))) void*)lA1, 16, 0, 0);
        __builtin_amdgcn_global_load_lds(
            (const __attribute__((address_space(1))) void*)(b0 + kt),
            (__attribute__((address_space(3))) void*)lB0, 16, 0, 0);
        __builtin_amdgcn_global_load_lds(
            (const __attribute__((address_space(1))) void*)(b1 + kt),
            (__attribute__((address_space(3))) void*)lB1, 16, 0, 0);
        __syncthreads();

        f16x8 fa[4], fb[4];
#pragma unroll
        for (int i = 0; i < 4; i++) {
            fa[i] = *(const f16x8*)&sA[(wm + i * 16 + fr) * 32 + quad * 8];
            fb[i] = *(const f16x8*)&sB[(wn + i * 16 + fr) * 32 + quad * 8];
        }
#pragma unroll
        for (int i = 0; i < 4; i++)
#pragma unroll
            for (int j = 0; j < 4; j++)
                acc[i][j] = __builtin_amdgcn_mfma_f32_16x16x32_f16(fa[i], fb[j], acc[i][j], 0, 0, 0);
        __syncthreads();
    }

    // C/D layout (measured m89/m91): col = lane&15, row = quad*4 + reg
#pragma unroll
    for (int i = 0; i < 4; i++) {
        int mbase = row0 + wm + i * 16 + quad * 4;
#pragma unroll
        for (int j = 0; j < 4; j++) {
            int n = col0 + wn + j * 16 + fr;
#pragma unroll
            for (int r = 0; r < 4; r++) {
                int m = mbase + r;
                if (m < M) C[(size_t)m * Nn + n] = (_Float16)acc[i][j][r];
            }
        }
    }
}

// ---------------------------------------------------------------------------
// fp32 tiled GEMM (kept for the small 256x256 projection)
// ---------------------------------------------------------------------------
template <int ACT>   // 0 = none, 1 = relu
__global__ __launch_bounds__(256) void gemm_kernel(
    const float* __restrict__ A, const float* __restrict__ B,
    const float* __restrict__ bias, float* __restrict__ C,
    int M, int K, int Nn)
{
    __shared__ float As[8][132];
    __shared__ float Bs[8][132];

    int tid = threadIdx.x;
    int tx = tid & 15, ty = tid >> 4;
    int row0 = blockIdx.y * 128, col0 = blockIdx.x * 128;

    int ar = tid >> 1;
    int aq = (tid & 1) * 4;
    int br = tid >> 5;
    int bc = (tid & 31) * 4;
    const float* Ap = A + (size_t)(row0 + ar) * K + aq;
    const float* Bp = B + (size_t)br * Nn + col0 + bc;
    bool aok = (row0 + ar) < M;

    float acc[8][8] = {};

    for (int kt = 0; kt < K; kt += 8) {
        float4 av = aok ? *(const float4*)(Ap + kt) : make_float4(0.f, 0.f, 0.f, 0.f);
        float4 bv = *(const float4*)(Bp + (size_t)kt * Nn);
        __syncthreads();
        As[aq + 0][ar] = av.x; As[aq + 1][ar] = av.y;
        As[aq + 2][ar] = av.z; As[aq + 3][ar] = av.w;
        *(float4*)&Bs[br][bc] = bv;
        __syncthreads();
#pragma unroll
        for (int kk = 0; kk < 8; kk++) {
            const float4 a0 = *(const float4*)&As[kk][ty * 8];
            const float4 a1 = *(const float4*)&As[kk][ty * 8 + 4];
            const float4 b0 = *(const float4*)&Bs[kk][tx * 4];
            const float4 b1 = *(const float4*)&Bs[kk][64 + tx * 4];
            float av8[8] = {a0.x, a0.y, a0.z, a0.w, a1.x, a1.y, a1.z, a1.w};
            float bv8[8] = {b0.x, b0.y, b0.z, b0.w, b1.x, b1.y, b1.z, b1.w};
#pragma unroll
            for (int i = 0; i < 8; i++)
#pragma unroll
                for (int j = 0; j < 8; j++)
                    acc[i][j] = fmaf(av8[i], bv8[j], acc[i][j]);
        }
    }

#pragma unroll
    for (int i = 0; i < 8; i++) {
        int r = row0 + ty * 8 + i;
        if (r >= M) continue;
        float out8[8];
#pragma unroll
        for (int j = 0; j < 8; j++) {
            int cc = (j < 4) ? (tx * 4 + j) : (64 + tx * 4 + (j - 4));
            float v = acc[i][j];
            if (bias) v += bias[col0 + cc];
            if (ACT == 1) v = fmaxf(v, 0.f);
            out8[j] = v;
        }
        float* cp = C + (size_t)r * Nn + col0;
        *(float4*)(cp + tx * 4)      = make_float4(out8[0], out8[1], out8[2], out8[3]);
        *(float4*)(cp + 64 + tx * 4) = make_float4(out8[4], out8[5], out8[6], out8[7]);
    }
}

// ---------------------------------------------------------------------------
// per-node attention coefficients from fp16 H: one f16x8 load per lane
// covers a head's 256 channels with 32 lanes.
// ---------------------------------------------------------------------------
__global__ __launch_bounds__(256) void attn_kernel(
    const _Float16* __restrict__ H, const float* __restrict__ a_src,
    const float* __restrict__ a_dst, float* __restrict__ as_out,
    float* __restrict__ ad_out)
{
    int n = blockIdx.x;
    int t = threadIdx.x;
    int h = t >> 5, l = t & 31;
    f16x8 hv = *(const f16x8*)&H[(size_t)n * HC + h * HID + l * 8];
    const float* asp = a_src + h * HID + l * 8;
    const float* adp = a_dst + h * HID + l * 8;
    float sa = 0.f, sd = 0.f;
#pragma unroll
    for (int q = 0; q < 8; q++) {
        float v = (float)hv[q];
        sa = fmaf(v, asp[q], sa);
        sd = fmaf(v, adp[q], sd);
    }
#pragma unroll
    for (int o = 16; o > 0; o >>= 1) {
        sa += __shfl_xor(sa, o, 32);
        sd += __shfl_xor(sd, o, 32);
    }
    if (l == 0) { as_out[n * HEADS + h] = sa; ad_out[n * HEADS + h] = sd; }
}

// ---------------------------------------------------------------------------
// per-dst-node gather aggregation with segment softmax.  H is fp16.
// thread t covers 8 consecutive channels of head t>>5 -> one 16B load/edge.
// MODE 0: elu(sum + b1) -> fp16 [MPAD, HC]; blocks n>=NNODES just zero-pad.
// MODE 1: mean over heads + b2 -> fp32 [N, HID]
// ---------------------------------------------------------------------------
template <int MODE>
__global__ __launch_bounds__(256) void agg_kernel(
    const _Float16* __restrict__ H, const float* __restrict__ as_,
    const float* __restrict__ ad_, const float* __restrict__ bias,
    const int* __restrict__ indptr, const int* __restrict__ sorted,
    const int* __restrict__ ei, float* __restrict__ outf,
    _Float16* __restrict__ outh)
{
    __shared__ float m8[HEADS], d8[HEADS], adl[HEADS];
    __shared__ int   srcl[64];
    __shared__ float al[64][HEADS];
    __shared__ float red[HC];          // MODE 1 cross-head reduction

    int n = blockIdx.x;
    int t = threadIdx.x;

    if (MODE == 0 && n >= NNODES) {    // pad rows for the next MFMA GEMM
        _Float16 z8[8] = {};
        *(f16x8*)&outh[(size_t)n * HC + t * 8] = *(f16x8*)z8;
        return;
    }

    int start = indptr[n];
    int deg = indptr[n + 1] - start;

    if (t < HEADS) adl[t] = ad_[n * HEADS + t];
    __syncthreads();

    int h = t >> 5, l = t & 31;
    float adh = adl[h];

    float mx = -1e30f;
    for (int j = l; j < deg; j += 32) {
        int e = sorted[start + j];
        int s = edge_src(ei, e);
        float v = as_[s * HEADS + h] + adh;
        v = (v >= 0.f) ? v : NEG_SLOPE * v;
        mx = fmaxf(mx, v);
    }
#pragma unroll
    for (int o = 16; o > 0; o >>= 1) mx = fmaxf(mx, __shfl_xor(mx, o, 32));

    float sm = 0.f;
    for (int j = l; j < deg; j += 32) {
        int e = sorted[start + j];
        int s = edge_src(ei, e);
        float v = as_[s * HEADS + h] + adh;
        v = (v >= 0.f) ? v : NEG_SLOPE * v;
        sm += expf(v - mx);
    }
#pragma unroll
    for (int o = 16; o > 0; o >>= 1) sm += __shfl_xor(sm, o, 32);
    if (l == 0) { m8[h] = mx; d8[h] = sm; }

    // gather phase: thread t -> head hh, channels c8..c8+7
    int hh = t >> 5, c8 = (t & 31) * 8;
    const size_t hoff = (size_t)hh * HID + c8;
    float acc[8] = {};
    for (int base = 0; base < deg; base += 64) {
        int cntc = min(64, deg - base);
        __syncthreads();
        if (t < cntc) srcl[t] = edge_src(ei, sorted[start + base + t]);
        __syncthreads();
        {
            int j = t & 63, h0 = t >> 6;
            if (j < cntc) {
#pragma unroll
                for (int q = 0; q < 2; q++) {
                    int hx = h0 + q * 4;
                    float v = as_[srcl[j] * HEADS + hx] + adl[hx];
                    v = (v >= 0.f) ? v : NEG_SLOPE * v;
                    al[j][hx] = expf(v - m8[hx]) / (d8[hx] + 1e-16f);
                }
            }
        }
        __syncthreads();
        for (int jj = 0; jj < cntc; jj++) {
            int s = srcl[jj];
            f16x8 hv = *(const f16x8*)&H[(size_t)s * HC + hoff];
            float a = al[jj][hh];
#pragma unroll
            for (int q = 0; q < 8; q++)
                acc[q] = fmaf(a, (float)hv[q], acc[q]);
        }
    }

    if (MODE == 0) {
        _Float16 o8[8];
#pragma unroll
        for (int q = 0; q < 8; q++) {
            float v = acc[q] + bias[hoff + q];
            v = (v > 0.f) ? v : expm1f(v);          // ELU (alpha=1)
            o8[q] = (_Float16)v;
        }
        *(f16x8*)&outh[(size_t)n * HC + hoff] = *(f16x8*)o8;
    } else {
#pragma unroll
        for (int q = 0; q < 8; q++) red[hoff + q] = acc[q];
        __syncthreads();
        float s = 0.f;
#pragma unroll
        for (int h2 = 0; h2 < HEADS; h2++) s += red[h2 * HID + t];
        outf[(size_t)n * HID + t] = s * 0.125f + bias[t];
    }
}

// ---------------------------------------------------------------------------
extern "C" void kernel_launch(void* const* d_in, const int* in_sizes, int n_in,
                              void* d_out, int out_size, void* d_ws, size_t ws_size,
                              hipStream_t stream)
{
    const float* x      = (const float*)d_in[0];
    const int*   ei     = (const int*)  d_in[1];
    const float* W1     = (const float*)d_in[2];
    const float* a_src1 = (const float*)d_in[3];
    const float* a_dst1 = (const float*)d_in[4];
    const float* b1     = (const float*)d_in[5];
    const float* W2     = (const float*)d_in[6];
    const float* a_src2 = (const float*)d_in[7];
    const float* a_dst2 = (const float*)d_in[8];
    const float* b2     = (const float*)d_in[9];
    const float* Wp     = (const float*)d_in[10];
    const float* bp     = (const float*)d_in[11];
    float* out = (float*)d_out;

    char* ws = (char*)d_ws;
    size_t off = 0;
    auto alloc = [&](size_t bytes) -> char* {
        char* p = ws + off;
        off += (bytes + 255) & ~(size_t)255;
        return p;
    };
    _Float16* Hbuf = (_Float16*)alloc((size_t)NNODES * HC * 2);          // 41 MB (H1, then H2)
    _Float16* A2   = (_Float16*)alloc((size_t)MPAD * HC * 2);            // 41.4 MB
    _Float16* W1t  = (_Float16*)alloc((size_t)HC * IN_DIM * 2);          // 3.1 MB
    _Float16* W2t  = (_Float16*)alloc((size_t)HC * HC * 2);              // 8.4 MB
    _Float16* xh   = (_Float16*)alloc((size_t)MPAD * IN_DIM * 2);        // 15.5 MB
    float* asad   = (float*)alloc((size_t)4 * NNODES * HEADS * sizeof(float));
    float* as1 = asad;
    float* ad1 = asad + (size_t)NNODES * HEADS;
    float* as2 = asad + (size_t)2 * NNODES * HEADS;
    float* ad2 = asad + (size_t)3 * NNODES * HEADS;
    int*   cnt    = (int*)  alloc((size_t)NNODES * sizeof(int));
    int*   cur    = (int*)  alloc((size_t)NNODES * sizeof(int));
    int*   indptr = (int*)  alloc((size_t)(NNODES + 1) * sizeof(int));
    int*   sorted = (int*)  alloc((size_t)E_TOT * sizeof(int));
    float* out2   = (float*)alloc((size_t)NNODES * HID * sizeof(float)); // 10.2 MB

    // --- CSR build ---
    hipMemsetAsync(cnt, 0, NNODES * sizeof(int), stream);
    hipMemsetAsync(cur, 0, NNODES * sizeof(int), stream);
    count_kernel<<<(E_TOT + 255) / 256, 256, 0, stream>>>(ei, cnt);
    scan_kernel<<<1, 1024, 0, stream>>>(cnt, indptr);
    scatter_kernel<<<(E_TOT + 255) / 256, 256, 0, stream>>>(ei, indptr, cur, sorted);

    // --- preprocessing: fp16 conversions + weight transposes ---
    cvt_kernel<<<(MPAD * IN_DIM / 4 + 255) / 256, 256, 0, stream>>>(
        x, xh, NNODES, IN_DIM, MPAD);
    dim3 tb(32, 8);
    tcvt_kernel<<<dim3(HC / 32, IN_DIM / 32), tb, 0, stream>>>(W1, W1t, IN_DIM, HC);
    tcvt_kernel<<<dim3(HC / 32, HC / 32), tb, 0, stream>>>(W2, W2t, HC, HC);

    dim3 gMf(HC / 128, MPAD / 128);   // 16 x 79

    // Layer 1: H1 = x @ W1 (fp16 MFMA)
    mfma_gemm_kernel<<<gMf, 256, 0, stream>>>(xh, W1t, Hbuf, NNODES, IN_DIM, HC);
    attn_kernel<<<NNODES, 256, 0, stream>>>(Hbuf, a_src1, a_dst1, as1, ad1);
    agg_kernel<0><<<MPAD, 256, 0, stream>>>(Hbuf, as1, ad1, b1, indptr, sorted, ei,
                                            nullptr, A2);

    // Layer 2: H2 = elu_agg @ W2 (fp16 MFMA)
    mfma_gemm_kernel<<<gMf, 256, 0, stream>>>(A2, W2t, Hbuf, NNODES, HC, HC);
    attn_kernel<<<NNODES, 256, 0, stream>>>(Hbuf, a_src2, a_dst2, as2, ad2);
    agg_kernel<1><<<NNODES, 256, 0, stream>>>(Hbuf, as2, ad2, b2, indptr, sorted, ei,
                                              out2, nullptr);

    // Projection + ReLU (fp32, small)
    dim3 gProj(HID / 128, (NNODES + 127) / 128);
    gemm_kernel<1><<<gProj, 256, 0, stream>>>(out2, Wp, bp, out, NNODES, HID, HID);
}

// Round 7
// 474.669 us; speedup vs baseline: 3.7031x; 1.0863x over previous
//
#include <hip/hip_runtime.h>
#include <cstdint>
#include <cstddef>

#define IN_DIM  768
#define NNODES  10000
#define MPAD    10112        // 79 * 128
#define NEDGES  80000
#define E_TOT   90000        // edges + self loops
#define HEADS   8
#define HID     256
#define HC      2048         // HEADS*HID
#define NEG_SLOPE 0.2f

typedef _Float16 __attribute__((ext_vector_type(8))) f16x8;
typedef float    __attribute__((ext_vector_type(4))) f32x4;

// ---------------------------------------------------------------------------
// edge helpers: edge ids [0,NEDGES) are real edges, [NEDGES,E_TOT) self loops
// ---------------------------------------------------------------------------
__device__ __forceinline__ int edge_src(const int* __restrict__ ei, int e) {
    return (e < NEDGES) ? ei[e] : (e - NEDGES);
}
__device__ __forceinline__ int edge_dst(const int* __restrict__ ei, int e) {
    return (e < NEDGES) ? ei[NEDGES + e] : (e - NEDGES);
}

// ---------------------------------------------------------------------------
// CSR build: count -> scan -> scatter (int atomics only; fp path is gather)
// ---------------------------------------------------------------------------
__global__ void count_kernel(const int* __restrict__ ei, int* __restrict__ cnt) {
    int e = blockIdx.x * 256 + threadIdx.x;
    if (e < E_TOT) atomicAdd(&cnt[edge_dst(ei, e)], 1);
}

__global__ void scan_kernel(const int* __restrict__ cnt, int* __restrict__ indptr) {
    __shared__ int sums[1024];
    const int CH = 10;
    int t = threadIdx.x;
    int base = t * CH;
    int s = 0;
#pragma unroll
    for (int i = 0; i < CH; i++) { int idx = base + i; if (idx < NNODES) s += cnt[idx]; }
    sums[t] = s;
    __syncthreads();
    for (int off = 1; off < 1024; off <<= 1) {
        int v = (t >= off) ? sums[t - off] : 0;
        __syncthreads();
        sums[t] += v;
        __syncthreads();
    }
    int run = (t == 0) ? 0 : sums[t - 1];
#pragma unroll
    for (int i = 0; i < CH; i++) {
        int idx = base + i;
        if (idx < NNODES) { indptr[idx] = run; run += cnt[idx]; }
    }
    if (t == 0) indptr[NNODES] = E_TOT;
}

__global__ void scatter_kernel(const int* __restrict__ ei, const int* __restrict__ indptr,
                               int* __restrict__ cur, int* __restrict__ sorted) {
    int e = blockIdx.x * 256 + threadIdx.x;
    if (e < E_TOT) {
        int d = edge_dst(ei, e);
        int pos = atomicAdd(&cur[d], 1);
        sorted[indptr[d] + pos] = e;
    }
}

// ---------------------------------------------------------------------------
// convert x [rows, cols] fp32 -> fp16 [prows, cols], zero-padded rows
// ---------------------------------------------------------------------------
__global__ void cvt_kernel(const float* __restrict__ src,
                           _Float16* __restrict__ dst,
                           int rows, int cols, int prows) {
    int i = blockIdx.x * 256 + threadIdx.x;
    int total = (prows * cols) >> 2;
    if (i >= total) return;
    size_t e = (size_t)i * 4;
    int r = (int)(e / cols);
    float4 v = (r < rows) ? *(const float4*)(src + e) : make_float4(0.f, 0.f, 0.f, 0.f);
    _Float16 h4[4] = {(_Float16)v.x, (_Float16)v.y, (_Float16)v.z, (_Float16)v.w};
    *(ushort4*)(dst + e) = *(ushort4*)h4;
}

// ---------------------------------------------------------------------------
// transpose + convert: W [K, N] fp32 -> Wt [N, K] fp16.  block (32,8)
// ---------------------------------------------------------------------------
__global__ __launch_bounds__(256) void tcvt_kernel(
    const float* __restrict__ W, _Float16* __restrict__ T, int K, int N) {
    __shared__ float tile[32][33];
    int tx = threadIdx.x, ty = threadIdx.y;
    int bx = blockIdx.x, by = blockIdx.y;   // bx over N tiles, by over K tiles
#pragma unroll
    for (int q = 0; q < 4; q++)
        tile[ty + q * 8][tx] = W[(size_t)(by * 32 + ty + q * 8) * N + bx * 32 + tx];
    __syncthreads();
#pragma unroll
    for (int q = 0; q < 4; q++) {
        float v = tile[tx][ty + q * 8];
        T[(size_t)(bx * 32 + ty + q * 8) * K + by * 32 + tx] = (_Float16)v;
    }
}

// ---------------------------------------------------------------------------
// fp16 MFMA GEMM:  C[M,Nn] = A[Mpad,K] @ B[Nn,K]^T   (R5-proven BK=32 body)
// 128x128 tile, BK=32, 256 threads, global_load_lds width=16.
// swz=1: XCD-aware remap (requires gridDim.x==16): each XCD (id%8
// heuristic) owns 2 column-blocks -> its B slice stays L2-resident.
// EPI=0: store fp16 C.  EPI=1: store fp32 relu(C + bias[n]).
// Requires K%32==0, Nn%128==0, grid.y*128 <= Mpad (A rows padded+zeroed).
// ---------------------------------------------------------------------------
template <int EPI>
__global__ __launch_bounds__(256) void mfma_gemm_kernel(
    const _Float16* __restrict__ A, const _Float16* __restrict__ B,
    void* __restrict__ Cout, const float* __restrict__ bias,
    int M, int K, int Nn, int swz)
{
    __shared__ __align__(16) _Float16 sA[128 * 32];
    __shared__ __align__(16) _Float16 sB[128 * 32];

    int t = threadIdx.x;
    int bx = blockIdx.x, by = blockIdx.y;
    if (swz) {                       // gridDim.x == 16 only
        int id = by * 16 + bx;
        int xcd = id & 7, slot = id >> 3;
        bx = 2 * xcd + (slot & 1);
        by = slot >> 1;
    }
    int row0 = by * 128;
    int col0 = bx * 128;

    // staging: slot s covers (m = s>>2, k-offset = (s&3)*8); each slot = 16B
    int s0 = t, s1 = t + 256;
    int m0 = s0 >> 2, k0 = (s0 & 3) * 8;
    int m1 = s1 >> 2, k1 = (s1 & 3) * 8;
    const _Float16* a0 = A + (size_t)(row0 + m0) * K + k0;
    const _Float16* a1 = A + (size_t)(row0 + m1) * K + k1;
    const _Float16* b0 = B + (size_t)(col0 + m0) * K + k0;
    const _Float16* b1 = B + (size_t)(col0 + m1) * K + k1;

    int w = t >> 6, lane = t & 63;
    _Float16* lA0 = &sA[(w * 64) * 8];
    _Float16* lA1 = &sA[(w * 64 + 256) * 8];
    _Float16* lB0 = &sB[(w * 64) * 8];
    _Float16* lB1 = &sB[(w * 64 + 256) * 8];

    int wm = (w & 1) * 64, wn = (w >> 1) * 64;
    int fr = lane & 15, quad = lane >> 4;

    f32x4 acc[4][4];
#pragma unroll
    for (int i = 0; i < 4; i++)
#pragma unroll
        for (int j = 0; j < 4; j++) acc[i][j] = {0.f, 0.f, 0.f, 0.f};

    for (int kt = 0; kt < K; kt += 32) {
        __builtin_amdgcn_global_load_lds(
            (const __attribute__((address_space(1))) void*)(a0 + kt),
            (__attribute__((address_space(3))) void*)lA0, 16, 0, 0);
        __builtin_amdgcn_global_load_lds(
            (const __attribute__((address_space(1))) void*)(a1 + kt),
            (__attribute__((address_space(3))) void*)lA1, 16, 0, 0);
        __builtin_amdgcn_global_load_lds(
            (const __attribute__((address_space(1))) void*)(b0 + kt),
            (__attribute__((address_space(3))) void*)lB0, 16, 0, 0);
        __builtin_amdgcn_global_load_lds(
            (const __attribute__((address_space(1))) void*)(b1 + kt),
            (__attribute__((address_space(3))) void*)lB1, 16, 0, 0);
        __syncthreads();

        f16x8 fa[4], fb[4];
#pragma unroll
        for (int i = 0; i < 4; i++) {
            fa[i] = *(const f16x8*)&sA[(wm + i * 16 + fr) * 32 + quad * 8];
            fb[i] = *(const f16x8*)&sB[(wn + i * 16 + fr) * 32 + quad * 8];
        }
#pragma unroll
        for (int i = 0; i < 4; i++)
#pragma unroll
            for (int j = 0; j < 4; j++)
                acc[i][j] = __builtin_amdgcn_mfma_f32_16x16x32_f16(fa[i], fb[j], acc[i][j], 0, 0, 0);
        __syncthreads();
    }

    // C/D layout (measured m89/m91): col = lane&15, row = quad*4 + reg
    if (EPI == 0) {
        _Float16* C = (_Float16*)Cout;
#pragma unroll
        for (int i = 0; i < 4; i++) {
            int mbase = row0 + wm + i * 16 + quad * 4;
#pragma unroll
            for (int j = 0; j < 4; j++) {
                int n = col0 + wn + j * 16 + fr;
#pragma unroll
                for (int r = 0; r < 4; r++) {
                    int m = mbase + r;
                    if (m < M) C[(size_t)m * Nn + n] = (_Float16)acc[i][j][r];
                }
            }
        }
    } else {
        float* C = (float*)Cout;
        float bv[4];
#pragma unroll
        for (int j = 0; j < 4; j++) bv[j] = bias[col0 + wn + j * 16 + fr];
#pragma unroll
        for (int i = 0; i < 4; i++) {
            int mbase = row0 + wm + i * 16 + quad * 4;
#pragma unroll
            for (int j = 0; j < 4; j++) {
                int n = col0 + wn + j * 16 + fr;
#pragma unroll
                for (int r = 0; r < 4; r++) {
                    int m = mbase + r;
                    if (m < M) C[(size_t)m * Nn + n] = fmaxf(acc[i][j][r] + bv[j], 0.f);
                }
            }
        }
    }
}

// ---------------------------------------------------------------------------
// per-node attention coefficients from fp16 H: one f16x8 load per lane
// covers a head's 256 channels with 32 lanes.
// ---------------------------------------------------------------------------
__global__ __launch_bounds__(256) void attn_kernel(
    const _Float16* __restrict__ H, const float* __restrict__ a_src,
    const float* __restrict__ a_dst, float* __restrict__ as_out,
    float* __restrict__ ad_out)
{
    int n = blockIdx.x;
    int t = threadIdx.x;
    int h = t >> 5, l = t & 31;
    f16x8 hv = *(const f16x8*)&H[(size_t)n * HC + h * HID + l * 8];
    const float* asp = a_src + h * HID + l * 8;
    const float* adp = a_dst + h * HID + l * 8;
    float sa = 0.f, sd = 0.f;
#pragma unroll
    for (int q = 0; q < 8; q++) {
        float v = (float)hv[q];
        sa = fmaf(v, asp[q], sa);
        sd = fmaf(v, adp[q], sd);
    }
#pragma unroll
    for (int o = 16; o > 0; o >>= 1) {
        sa += __shfl_xor(sa, o, 32);
        sd += __shfl_xor(sd, o, 32);
    }
    if (l == 0) { as_out[n * HEADS + h] = sa; ad_out[n * HEADS + h] = sd; }
}

// ---------------------------------------------------------------------------
// per-dst-node gather aggregation with segment softmax.  H is fp16.
// thread t covers 8 consecutive channels of head t>>5 -> one 16B load/edge.
// MODE 0: elu(sum + b1) -> fp16 [MPAD, HC]
// MODE 1: (mean over heads + b2) -> fp16 [MPAD, HID]   (feeds MFMA proj)
// blocks n >= NNODES just zero-pad (grid = MPAD for both modes).
// ---------------------------------------------------------------------------
template <int MODE>
__global__ __launch_bounds__(256) void agg_kernel(
    const _Float16* __restrict__ H, const float* __restrict__ as_,
    const float* __restrict__ ad_, const float* __restrict__ bias,
    const int* __restrict__ indptr, const int* __restrict__ sorted,
    const int* __restrict__ ei, _Float16* __restrict__ outh)
{
    __shared__ float m8[HEADS], d8[HEADS], adl[HEADS];
    __shared__ int   srcl[64];
    __shared__ float al[64][HEADS];
    __shared__ float red[HC];          // MODE 1 cross-head reduction

    int n = blockIdx.x;
    int t = threadIdx.x;

    if (n >= NNODES) {                 // pad rows for the next MFMA GEMM
        if (MODE == 0) {
            _Float16 z8[8] = {};
            *(f16x8*)&outh[(size_t)n * HC + t * 8] = *(f16x8*)z8;
        } else {
            outh[(size_t)n * HID + t] = (_Float16)0.f;
        }
        return;
    }

    int start = indptr[n];
    int deg = indptr[n + 1] - start;

    if (t < HEADS) adl[t] = ad_[n * HEADS + t];
    __syncthreads();

    int h = t >> 5, l = t & 31;
    float adh = adl[h];

    float mx = -1e30f;
    for (int j = l; j < deg; j += 32) {
        int e = sorted[start + j];
        int s = edge_src(ei, e);
        float v = as_[s * HEADS + h] + adh;
        v = (v >= 0.f) ? v : NEG_SLOPE * v;
        mx = fmaxf(mx, v);
    }
#pragma unroll
    for (int o = 16; o > 0; o >>= 1) mx = fmaxf(mx, __shfl_xor(mx, o, 32));

    float sm = 0.f;
    for (int j = l; j < deg; j += 32) {
        int e = sorted[start + j];
        int s = edge_src(ei, e);
        float v = as_[s * HEADS + h] + adh;
        v = (v >= 0.f) ? v : NEG_SLOPE * v;
        sm += expf(v - mx);
    }
#pragma unroll
    for (int o = 16; o > 0; o >>= 1) sm += __shfl_xor(sm, o, 32);
    if (l == 0) { m8[h] = mx; d8[h] = sm; }

    // gather phase: thread t -> head hh, channels c8..c8+7
    int hh = t >> 5, c8 = (t & 31) * 8;
    const size_t hoff = (size_t)hh * HID + c8;
    float acc[8] = {};
    for (int base = 0; base < deg; base += 64) {
        int cntc = min(64, deg - base);
        __syncthreads();
        if (t < cntc) srcl[t] = edge_src(ei, sorted[start + base + t]);
        __syncthreads();
        {
            int j = t & 63, h0 = t >> 6;
            if (j < cntc) {
#pragma unroll
                for (int q = 0; q < 2; q++) {
                    int hx = h0 + q * 4;
                    float v = as_[srcl[j] * HEADS + hx] + adl[hx];
                    v = (v >= 0.f) ? v : NEG_SLOPE * v;
                    al[j][hx] = expf(v - m8[hx]) / (d8[hx] + 1e-16f);
                }
            }
        }
        __syncthreads();
        for (int jj = 0; jj < cntc; jj++) {
            int s = srcl[jj];
            f16x8 hv = *(const f16x8*)&H[(size_t)s * HC + hoff];
            float a = al[jj][hh];
#pragma unroll
            for (int q = 0; q < 8; q++)
                acc[q] = fmaf(a, (float)hv[q], acc[q]);
        }
    }

    if (MODE == 0) {
        _Float16 o8[8];
#pragma unroll
        for (int q = 0; q < 8; q++) {
            float v = acc[q] + bias[hoff + q];
            v = (v > 0.f) ? v : expm1f(v);          // ELU (alpha=1)
            o8[q] = (_Float16)v;
        }
        *(f16x8*)&outh[(size_t)n * HC + hoff] = *(f16x8*)o8;
    } else {
#pragma unroll
        for (int q = 0; q < 8; q++) red[hoff + q] = acc[q];
        __syncthreads();
        float s = 0.f;
#pragma unroll
        for (int h2 = 0; h2 < HEADS; h2++) s += red[h2 * HID + t];
        outh[(size_t)n * HID + t] = (_Float16)(s * 0.125f + bias[t]);
    }
}

// ---------------------------------------------------------------------------
extern "C" void kernel_launch(void* const* d_in, const int* in_sizes, int n_in,
                              void* d_out, int out_size, void* d_ws, size_t ws_size,
                              hipStream_t stream)
{
    const float* x      = (const float*)d_in[0];
    const int*   ei     = (const int*)  d_in[1];
    const float* W1     = (const float*)d_in[2];
    const float* a_src1 = (const float*)d_in[3];
    const float* a_dst1 = (const float*)d_in[4];
    const float* b1     = (const float*)d_in[5];
    const float* W2     = (const float*)d_in[6];
    const float* a_src2 = (const float*)d_in[7];
    const float* a_dst2 = (const float*)d_in[8];
    const float* b2     = (const float*)d_in[9];
    const float* Wp     = (const float*)d_in[10];
    const float* bp     = (const float*)d_in[11];
    float* out = (float*)d_out;

    char* ws = (char*)d_ws;
    size_t off = 0;
    auto alloc = [&](size_t bytes) -> char* {
        char* p = ws + off;
        off += (bytes + 255) & ~(size_t)255;
        return p;
    };
    _Float16* Hbuf = (_Float16*)alloc((size_t)NNODES * HC * 2);          // 41 MB (H1, then H2)
    _Float16* A2   = (_Float16*)alloc((size_t)MPAD * HC * 2);            // 41.4 MB
    _Float16* W1t  = (_Float16*)alloc((size_t)HC * IN_DIM * 2);          // 3.1 MB
    _Float16* W2t  = (_Float16*)alloc((size_t)HC * HC * 2);              // 8.4 MB
    _Float16* Wpt  = (_Float16*)alloc((size_t)HID * HID * 2);            // 128 KB
    _Float16* xh   = (_Float16*)alloc((size_t)MPAD * IN_DIM * 2);        // 15.5 MB
    _Float16* out2h = (_Float16*)alloc((size_t)MPAD * HID * 2);          // 5.2 MB
    float* asad   = (float*)alloc((size_t)4 * NNODES * HEADS * sizeof(float));
    float* as1 = asad;
    float* ad1 = asad + (size_t)NNODES * HEADS;
    float* as2 = asad + (size_t)2 * NNODES * HEADS;
    float* ad2 = asad + (size_t)3 * NNODES * HEADS;
    int*   cnt    = (int*)  alloc((size_t)NNODES * sizeof(int));
    int*   cur    = (int*)  alloc((size_t)NNODES * sizeof(int));
    int*   indptr = (int*)  alloc((size_t)(NNODES + 1) * sizeof(int));
    int*   sorted = (int*)  alloc((size_t)E_TOT * sizeof(int));

    // --- CSR build ---
    hipMemsetAsync(cnt, 0, NNODES * sizeof(int), stream);
    hipMemsetAsync(cur, 0, NNODES * sizeof(int), stream);
    count_kernel<<<(E_TOT + 255) / 256, 256, 0, stream>>>(ei, cnt);
    scan_kernel<<<1, 1024, 0, stream>>>(cnt, indptr);
    scatter_kernel<<<(E_TOT + 255) / 256, 256, 0, stream>>>(ei, indptr, cur, sorted);

    // --- preprocessing: fp16 conversions + weight transposes ---
    cvt_kernel<<<(MPAD * IN_DIM / 4 + 255) / 256, 256, 0, stream>>>(
        x, xh, NNODES, IN_DIM, MPAD);
    dim3 tb(32, 8);
    tcvt_kernel<<<dim3(HC / 32, IN_DIM / 32), tb, 0, stream>>>(W1, W1t, IN_DIM, HC);
    tcvt_kernel<<<dim3(HC / 32, HC / 32), tb, 0, stream>>>(W2, W2t, HC, HC);
    tcvt_kernel<<<dim3(HID / 32, HID / 32), tb, 0, stream>>>(Wp, Wpt, HID, HID);

    dim3 gMf(HC / 128, MPAD / 128);   // 16 x 79

    // Layer 1: H1 = x @ W1 (fp16 MFMA, BK=32, XCD swizzle)
    mfma_gemm_kernel<0><<<gMf, 256, 0, stream>>>(xh, W1t, Hbuf, nullptr,
                                                 NNODES, IN_DIM, HC, 1);
    attn_kernel<<<NNODES, 256, 0, stream>>>(Hbuf, a_src1, a_dst1, as1, ad1);
    agg_kernel<0><<<MPAD, 256, 0, stream>>>(Hbuf, as1, ad1, b1, indptr, sorted, ei, A2);

    // Layer 2: H2 = elu_agg @ W2 (fp16 MFMA, BK=32, XCD swizzle)
    mfma_gemm_kernel<0><<<gMf, 256, 0, stream>>>(A2, W2t, Hbuf, nullptr,
                                                 NNODES, HC, HC, 1);
    attn_kernel<<<NNODES, 256, 0, stream>>>(Hbuf, a_src2, a_dst2, as2, ad2);
    agg_kernel<1><<<MPAD, 256, 0, stream>>>(Hbuf, as2, ad2, b2, indptr, sorted, ei, out2h);

    // Projection + ReLU (fp16 MFMA, bias+relu fp32 epilogue)
    dim3 gProj(HID / 128, MPAD / 128);   // 2 x 79
    mfma_gemm_kernel<1><<<gProj, 256, 0, stream>>>(out2h, Wpt, out, bp,
                                                   NNODES, HID, HID, 0);
}